// Round 1
// baseline (752.235 us; speedup 1.0000x reference)
//
#include <hip/hip_runtime.h>
#include <math.h>

#define NEG_SLOPE 0.2f

// ---------------- CSR build ----------------

__global__ void k_zero_i32(int* __restrict__ p, int n) {
  int i = blockIdx.x * 256 + threadIdx.x;
  if (i < n) p[i] = 0;
}

__global__ void k_count(const int* __restrict__ dst, int* __restrict__ counts, int E) {
  int i = blockIdx.x * 256 + threadIdx.x;
  if (i < E) atomicAdd(&counts[dst[i]], 1);
}

// single-block exclusive scan over counts[0..n) -> offsets, cursor
__global__ __launch_bounds__(1024) void k_scan(const int* __restrict__ counts,
                                               int* __restrict__ offsets,
                                               int* __restrict__ cursor, int n) {
  __shared__ int wsum[16];
  int tid = threadIdx.x;
  int lane = tid & 63, wid = tid >> 6;
  int carry = 0;
  for (int base = 0; base < n; base += 1024) {
    int i = base + tid;
    int v = (i < n) ? counts[i] : 0;
    int orig = v;
#pragma unroll
    for (int off = 1; off < 64; off <<= 1) {
      int u = __shfl_up(v, off, 64);
      if (lane >= off) v += u;
    }
    if (lane == 63) wsum[wid] = v;
    __syncthreads();
    if (wid == 0 && lane < 16) {
      int s = wsum[lane];
#pragma unroll
      for (int off = 1; off < 16; off <<= 1) {
        int u = __shfl_up(s, off, 64);
        if (lane >= off) s += u;
      }
      wsum[lane] = s;
    }
    __syncthreads();
    int wbase = (wid > 0) ? wsum[wid - 1] : 0;
    int tot = wsum[15];
    int excl = carry + wbase + (v - orig);
    if (i < n) { offsets[i] = excl; cursor[i] = excl; }
    carry += tot;
    __syncthreads();
  }
}

__global__ void k_fill(const int* __restrict__ src, const int* __restrict__ dst,
                       int* __restrict__ cursor, int* __restrict__ csr_src, int E) {
  int i = blockIdx.x * 256 + threadIdx.x;
  if (i < E) {
    int d = dst[i];
    int pos = atomicAdd(&cursor[d], 1);
    csr_src[pos] = src[i];
  }
}

// ---------------- Layer 1 GEMM: f1 = x @ W1  (N x 128) @ (128 x 256) ----------------
// 64x64 block tile, 4x4 per thread, K staged in chunks of 32.
__global__ __launch_bounds__(256) void k_gemm1(const float* __restrict__ x,
                                               const float* __restrict__ W,
                                               float* __restrict__ f, int n) {
  __shared__ __align__(16) float xs[32][64];  // [k][node]
  __shared__ __align__(16) float ws[32][64];  // [k][col]
  int tid = threadIdx.x;
  int tm = tid >> 4, tn = tid & 15;
  int m0 = blockIdx.x * 64;
  int c0 = blockIdx.y * 64;
  float acc[4][4];
#pragma unroll
  for (int i = 0; i < 4; ++i)
#pragma unroll
    for (int j = 0; j < 4; ++j) acc[i][j] = 0.f;

  for (int kb = 0; kb < 128; kb += 32) {
#pragma unroll
    for (int r = 0; r < 2; ++r) {
      int e = tid * 8 + r * 4;
      // x tile: 64 nodes x 32 k, stored transposed xs[k][node]
      int node = e >> 5, kk = e & 31;
      float4 v = make_float4(0.f, 0.f, 0.f, 0.f);
      int gn = m0 + node;
      if (gn < n) v = *(const float4*)(x + (size_t)gn * 128 + kb + kk);
      xs[kk + 0][node] = v.x; xs[kk + 1][node] = v.y;
      xs[kk + 2][node] = v.z; xs[kk + 3][node] = v.w;
      // W tile: 32 k x 64 cols
      int kw = e >> 6, cc = e & 63;
      *(float4*)(&ws[kw][cc]) = *(const float4*)(W + (size_t)(kb + kw) * 256 + c0 + cc);
    }
    __syncthreads();
#pragma unroll
    for (int k = 0; k < 32; ++k) {
      float4 a = *(float4*)(&xs[k][tm * 4]);
      float4 b = *(float4*)(&ws[k][tn * 4]);
      acc[0][0] += a.x * b.x; acc[0][1] += a.x * b.y; acc[0][2] += a.x * b.z; acc[0][3] += a.x * b.w;
      acc[1][0] += a.y * b.x; acc[1][1] += a.y * b.y; acc[1][2] += a.y * b.z; acc[1][3] += a.y * b.w;
      acc[2][0] += a.z * b.x; acc[2][1] += a.z * b.y; acc[2][2] += a.z * b.z; acc[2][3] += a.z * b.w;
      acc[3][0] += a.w * b.x; acc[3][1] += a.w * b.y; acc[3][2] += a.w * b.z; acc[3][3] += a.w * b.w;
    }
    __syncthreads();
  }
#pragma unroll
  for (int i = 0; i < 4; ++i) {
    int gn = m0 + tm * 4 + i;
    if (gn < n) {
      float4 v = make_float4(acc[i][0], acc[i][1], acc[i][2], acc[i][3]);
      *(float4*)(&f[(size_t)gn * 256 + c0 + tn * 4]) = v;
    }
  }
}

// ---------------- Layer 1 attention logits: el1/er1 [N,8] ----------------
__global__ __launch_bounds__(256) void k_attn1(const float* __restrict__ f,
                                               const float* __restrict__ al,
                                               const float* __restrict__ ar,
                                               float* __restrict__ el, float* __restrict__ er,
                                               int n) {
  int tid = threadIdx.x;
  int g = tid >> 5, lane32 = tid & 31;
  int gid = blockIdx.x * 8 + g;  // (node, head) pair, n*8 total (exact multiple)
  int node = gid >> 3, hh = gid & 7;
  float v = f[(size_t)node * 256 + hh * 32 + lane32];
  float a = v * al[hh * 32 + lane32];
  float b = v * ar[hh * 32 + lane32];
#pragma unroll
  for (int off = 16; off >= 1; off >>= 1) {
    a += __shfl_xor(a, off, 64);
    b += __shfl_xor(b, off, 64);
  }
  if (lane32 == 0) { el[node * 8 + hh] = a; er[node * 8 + hh] = b; }
}

// ---------------- Layer 1 aggregation: edge softmax + message sum + bias + ELU ----------------
// one block (256 thr = 8 heads x 32 dims) per dst node
__global__ __launch_bounds__(256) void k_agg1(const float* __restrict__ f,
                                              const float* __restrict__ el,
                                              const float* __restrict__ er,
                                              const int* __restrict__ offsets,
                                              const int* __restrict__ counts,
                                              const int* __restrict__ csr_src,
                                              const float* __restrict__ b1,
                                              float* __restrict__ hout, int n) {
  int node = blockIdx.x;
  int tid = threadIdx.x;
  int hh = tid >> 5;
  int start = offsets[node], deg = counts[node];
  float erv = er[node * 8 + hh];
  float m = -INFINITY, l = 0.f;
  for (int j = 0; j < deg; ++j) {
    int s = csr_src[start + j];
    float e = el[s * 8 + hh] + erv;
    e = (e >= 0.f) ? e : NEG_SLOPE * e;
    float mn = fmaxf(m, e);
    l = l * __expf(m - mn) + __expf(e - mn);
    m = mn;
  }
  float acc = 0.f;
  for (int j = 0; j < deg; ++j) {
    int s = csr_src[start + j];
    float e = el[s * 8 + hh] + erv;
    e = (e >= 0.f) ? e : NEG_SLOPE * e;
    acc += f[(size_t)s * 256 + tid] * __expf(e - m);
  }
  float o = (deg > 0) ? (acc / l) : 0.f;
  o += b1[tid];
  o = (o > 0.f) ? o : (__expf(o) - 1.f);  // ELU
  hout[(size_t)node * 256 + tid] = o;
}

// ---------------- Layer 2 GEMM: f2 = h @ W2 (N x 256)@(256 x 32), + el2/er2 ----------------
// one wave handles 4 nodes; lane: half = lane>>5 covers k-half, c = lane&31
__global__ __launch_bounds__(256) void k_gemm2(const float* __restrict__ h,
                                               const float* __restrict__ W2,
                                               const float* __restrict__ al2,
                                               const float* __restrict__ ar2,
                                               float* __restrict__ f2,
                                               float* __restrict__ el2,
                                               float* __restrict__ er2, int n) {
  int tid = threadIdx.x;
  int wave = tid >> 6, lane = tid & 63;
  int half = lane >> 5, c = lane & 31;
  int n0 = (blockIdx.x * 4 + wave) * 4;
  float acc[4] = {0.f, 0.f, 0.f, 0.f};
  float al_c = al2[c], ar_c = ar2[c];
  int k0 = half * 128;
  for (int k = k0; k < k0 + 128; ++k) {
    float w = W2[k * 32 + c];
#pragma unroll
    for (int i = 0; i < 4; ++i) {
      int nd = n0 + i;
      float hv = (nd < n) ? h[(size_t)nd * 256 + k] : 0.f;
      acc[i] += hv * w;
    }
  }
#pragma unroll
  for (int i = 0; i < 4; ++i) acc[i] += __shfl_xor(acc[i], 32, 64);
#pragma unroll
  for (int i = 0; i < 4; ++i) {
    int nd = n0 + i;
    float a = acc[i] * al_c, b = acc[i] * ar_c;
#pragma unroll
    for (int off = 16; off >= 1; off >>= 1) {
      a += __shfl_xor(a, off, 64);
      b += __shfl_xor(b, off, 64);
    }
    if (nd < n && half == 0) {
      f2[nd * 32 + c] = acc[i];
      if (c == 0) { el2[nd] = a; er2[nd] = b; }
    }
  }
}

// ---------------- Layer 2 aggregation -> output [N,32] ----------------
// 32-lane group per dst node, 8 nodes per block
__global__ __launch_bounds__(256) void k_agg2(const float* __restrict__ f2,
                                              const float* __restrict__ el2,
                                              const float* __restrict__ er2,
                                              const int* __restrict__ offsets,
                                              const int* __restrict__ counts,
                                              const int* __restrict__ csr_src,
                                              const float* __restrict__ b2,
                                              float* __restrict__ out, int n) {
  int tid = threadIdx.x;
  int g = tid >> 5, d = tid & 31;
  int node = blockIdx.x * 8 + g;  // n is multiple of 8 (50000/8=6250)
  int start = offsets[node], deg = counts[node];
  float erv = er2[node];
  float m = -INFINITY, l = 0.f;
  for (int j = 0; j < deg; ++j) {
    int s = csr_src[start + j];
    float e = el2[s] + erv;
    e = (e >= 0.f) ? e : NEG_SLOPE * e;
    float mn = fmaxf(m, e);
    l = l * __expf(m - mn) + __expf(e - mn);
    m = mn;
  }
  float acc = 0.f;
  for (int j = 0; j < deg; ++j) {
    int s = csr_src[start + j];
    float e = el2[s] + erv;
    e = (e >= 0.f) ? e : NEG_SLOPE * e;
    acc += f2[s * 32 + d] * __expf(e - m);
  }
  float o = (deg > 0) ? (acc / l) : 0.f;
  out[node * 32 + d] = o + b2[d];
}

// ---------------- launch ----------------

extern "C" void kernel_launch(void* const* d_in, const int* in_sizes, int n_in,
                              void* d_out, int out_size, void* d_ws, size_t ws_size,
                              hipStream_t stream) {
  const float* x   = (const float*)d_in[0];
  const int*   src = (const int*)d_in[1];
  const int*   dst = (const int*)d_in[2];
  const float* W1  = (const float*)d_in[3];
  const float* al1 = (const float*)d_in[4];
  const float* ar1 = (const float*)d_in[5];
  const float* b1  = (const float*)d_in[6];
  const float* W2  = (const float*)d_in[7];
  const float* al2 = (const float*)d_in[8];
  const float* ar2 = (const float*)d_in[9];
  const float* b2  = (const float*)d_in[10];
  float* out = (float*)d_out;

  int N = in_sizes[0] / 128;
  int E = in_sizes[1];

  char* w = (char*)d_ws;
  auto alloc = [&](size_t nelem) -> void* {
    void* p = (void*)w;
    w += ((nelem * 4 + 255) / 256) * 256;
    return p;
  };
  float* f1   = (float*)alloc((size_t)N * 256);
  float* h    = (float*)alloc((size_t)N * 256);
  float* el1  = (float*)alloc((size_t)N * 8);
  float* er1  = (float*)alloc((size_t)N * 8);
  float* f2   = (float*)alloc((size_t)N * 32);
  float* el2  = (float*)alloc(N);
  float* er2  = (float*)alloc(N);
  int* counts  = (int*)alloc(N);
  int* offsets = (int*)alloc(N);
  int* cursor  = (int*)alloc(N);
  int* csr_src = (int*)alloc(E);

  hipLaunchKernelGGL(k_zero_i32, dim3((N + 255) / 256), dim3(256), 0, stream, counts, N);
  hipLaunchKernelGGL(k_count, dim3((E + 255) / 256), dim3(256), 0, stream, dst, counts, E);
  hipLaunchKernelGGL(k_scan, dim3(1), dim3(1024), 0, stream, counts, offsets, cursor, N);
  hipLaunchKernelGGL(k_fill, dim3((E + 255) / 256), dim3(256), 0, stream, src, dst, cursor, csr_src, E);
  hipLaunchKernelGGL(k_gemm1, dim3((N + 63) / 64, 4), dim3(256), 0, stream, x, W1, f1, N);
  hipLaunchKernelGGL(k_attn1, dim3(N), dim3(256), 0, stream, f1, al1, ar1, el1, er1, N);
  hipLaunchKernelGGL(k_agg1, dim3(N), dim3(256), 0, stream, f1, el1, er1, offsets, counts, csr_src, b1, h, N);
  hipLaunchKernelGGL(k_gemm2, dim3((N + 15) / 16), dim3(256), 0, stream, h, W2, al2, ar2, f2, el2, er2, N);
  hipLaunchKernelGGL(k_agg2, dim3((N + 7) / 8), dim3(256), 0, stream, f2, el2, er2, offsets, counts, csr_src, b2, out, N);
}

// Round 3
// 632.858 us; speedup vs baseline: 1.1886x; 1.1886x over previous
//
#include <hip/hip_runtime.h>
#include <math.h>

#define NEG_SLOPE 0.2f

// ---------------- CSR build ----------------

__global__ void k_zero_i32(int* __restrict__ p, int n) {
  int i = blockIdx.x * 256 + threadIdx.x;
  if (i < n) p[i] = 0;
}

__global__ void k_count(const int* __restrict__ dst, int* __restrict__ counts, int E) {
  int i = blockIdx.x * 256 + threadIdx.x;
  if (i < E) atomicAdd(&counts[dst[i]], 1);
}

// single-block exclusive scan over counts[0..n) -> offsets, cursor
__global__ __launch_bounds__(1024) void k_scan(const int* __restrict__ counts,
                                               int* __restrict__ offsets,
                                               int* __restrict__ cursor, int n) {
  __shared__ int wsum[16];
  int tid = threadIdx.x;
  int lane = tid & 63, wid = tid >> 6;
  int carry = 0;
  for (int base = 0; base < n; base += 1024) {
    int i = base + tid;
    int v = (i < n) ? counts[i] : 0;
    int orig = v;
#pragma unroll
    for (int off = 1; off < 64; off <<= 1) {
      int u = __shfl_up(v, off, 64);
      if (lane >= off) v += u;
    }
    if (lane == 63) wsum[wid] = v;
    __syncthreads();
    if (wid == 0 && lane < 16) {
      int s = wsum[lane];
#pragma unroll
      for (int off = 1; off < 16; off <<= 1) {
        int u = __shfl_up(s, off, 64);
        if (lane >= off) s += u;
      }
      wsum[lane] = s;
    }
    __syncthreads();
    int wbase = (wid > 0) ? wsum[wid - 1] : 0;
    int tot = wsum[15];
    int excl = carry + wbase + (v - orig);
    if (i < n) { offsets[i] = excl; cursor[i] = excl; }
    carry += tot;
    __syncthreads();
  }
}

__global__ void k_fill(const int* __restrict__ src, const int* __restrict__ dst,
                       int* __restrict__ cursor, int* __restrict__ csr_src, int E) {
  int i = blockIdx.x * 256 + threadIdx.x;
  if (i < E) {
    int d = dst[i];
    int pos = atomicAdd(&cursor[d], 1);
    csr_src[pos] = src[i];
  }
}

// ---------------- Layer 1 GEMM: f1 = x @ W1  (N x 128) @ (128 x 256) ----------------
__global__ __launch_bounds__(256) void k_gemm1(const float* __restrict__ x,
                                               const float* __restrict__ W,
                                               float* __restrict__ f, int n) {
  __shared__ __align__(16) float xs[32][64];  // [k][node]
  __shared__ __align__(16) float ws[32][64];  // [k][col]
  int tid = threadIdx.x;
  int tm = tid >> 4, tn = tid & 15;
  int m0 = blockIdx.x * 64;
  int c0 = blockIdx.y * 64;
  float acc[4][4];
#pragma unroll
  for (int i = 0; i < 4; ++i)
#pragma unroll
    for (int j = 0; j < 4; ++j) acc[i][j] = 0.f;

  for (int kb = 0; kb < 128; kb += 32) {
#pragma unroll
    for (int r = 0; r < 2; ++r) {
      int e = tid * 8 + r * 4;
      int node = e >> 5, kk = e & 31;
      float4 v = make_float4(0.f, 0.f, 0.f, 0.f);
      int gn = m0 + node;
      if (gn < n) v = *(const float4*)(x + (size_t)gn * 128 + kb + kk);
      xs[kk + 0][node] = v.x; xs[kk + 1][node] = v.y;
      xs[kk + 2][node] = v.z; xs[kk + 3][node] = v.w;
      int kw = e >> 6, cc = e & 63;
      *(float4*)(&ws[kw][cc]) = *(const float4*)(W + (size_t)(kb + kw) * 256 + c0 + cc);
    }
    __syncthreads();
#pragma unroll
    for (int k = 0; k < 32; ++k) {
      float4 a = *(float4*)(&xs[k][tm * 4]);
      float4 b = *(float4*)(&ws[k][tn * 4]);
      acc[0][0] += a.x * b.x; acc[0][1] += a.x * b.y; acc[0][2] += a.x * b.z; acc[0][3] += a.x * b.w;
      acc[1][0] += a.y * b.x; acc[1][1] += a.y * b.y; acc[1][2] += a.y * b.z; acc[1][3] += a.y * b.w;
      acc[2][0] += a.z * b.x; acc[2][1] += a.z * b.y; acc[2][2] += a.z * b.z; acc[2][3] += a.z * b.w;
      acc[3][0] += a.w * b.x; acc[3][1] += a.w * b.y; acc[3][2] += a.w * b.z; acc[3][3] += a.w * b.w;
    }
    __syncthreads();
  }
#pragma unroll
  for (int i = 0; i < 4; ++i) {
    int gn = m0 + tm * 4 + i;
    if (gn < n) {
      float4 v = make_float4(acc[i][0], acc[i][1], acc[i][2], acc[i][3]);
      *(float4*)(&f[(size_t)gn * 256 + c0 + tn * 4]) = v;
    }
  }
}

// ---------------- Layer 1 attention logits: el1/er1 [N,8] ----------------
__global__ __launch_bounds__(256) void k_attn1(const float* __restrict__ f,
                                               const float* __restrict__ al,
                                               const float* __restrict__ ar,
                                               float* __restrict__ el, float* __restrict__ er,
                                               int n) {
  int tid = threadIdx.x;
  int g = tid >> 5, lane32 = tid & 31;
  int gid = blockIdx.x * 8 + g;
  int node = gid >> 3, hh = gid & 7;
  float v = f[(size_t)node * 256 + hh * 32 + lane32];
  float a = v * al[hh * 32 + lane32];
  float b = v * ar[hh * 32 + lane32];
#pragma unroll
  for (int off = 16; off >= 1; off >>= 1) {
    a += __shfl_xor(a, off, 64);
    b += __shfl_xor(b, off, 64);
  }
  if (lane32 == 0) { el[node * 8 + hh] = a; er[node * 8 + hh] = b; }
}

// ---------------- Layer 1 aggregation: edge-parallel softmax + coalesced gather ----------------
// one block (256 thr) per dst node; phase A: thread=edge (chunks of 256);
// phase B: thread=(head,dim), inner loop = FMA + broadcast weight only.
__global__ __launch_bounds__(256) void k_agg1(const float* __restrict__ f,
                                              const float* __restrict__ el,
                                              const float* __restrict__ er,
                                              const int* __restrict__ offsets,
                                              const int* __restrict__ counts,
                                              const int* __restrict__ csr_src,
                                              const float* __restrict__ b1,
                                              float* __restrict__ hout, int n) {
  const int node = blockIdx.x;
  const int tid = threadIdx.x;
  const int lane = tid & 63, wid = tid >> 6;
  const int hh = tid >> 5, dd = tid & 31;  // phase-B mapping
  __shared__ float s_w[8][257];            // [head][edge-in-chunk], pad -> conflict-free
  __shared__ int s_idx[256];
  __shared__ float redm[4][8], reds[4][8];
  __shared__ float mrun[8], lrun[8], alpha[8];

  int start = offsets[node], deg = counts[node];
  if (tid < 8) { mrun[tid] = -INFINITY; lrun[tid] = 0.f; }

  float er0[8];
  {
    float4 a = *(const float4*)(er + node * 8);
    float4 b = *(const float4*)(er + node * 8 + 4);
    er0[0] = a.x; er0[1] = a.y; er0[2] = a.z; er0[3] = a.w;
    er0[4] = b.x; er0[5] = b.y; er0[6] = b.z; er0[7] = b.w;
  }
  float acc = 0.f;
  __syncthreads();

  for (int c0 = 0; c0 < deg; c0 += 256) {
    int j = c0 + tid;
    float e[8];
    int s = 0;
    if (j < deg) {
      s = csr_src[start + j];
      float4 a = *(const float4*)(el + (size_t)s * 8);
      float4 b = *(const float4*)(el + (size_t)s * 8 + 4);
      float t0[8] = {a.x, a.y, a.z, a.w, b.x, b.y, b.z, b.w};
#pragma unroll
      for (int h = 0; h < 8; ++h) {
        float v = t0[h] + er0[h];
        e[h] = (v >= 0.f) ? v : NEG_SLOPE * v;
      }
    } else {
#pragma unroll
      for (int h = 0; h < 8; ++h) e[h] = -INFINITY;
    }
    // wave max-reduce (8 heads)
    float vm[8];
#pragma unroll
    for (int h = 0; h < 8; ++h) vm[h] = e[h];
#pragma unroll
    for (int off = 32; off >= 1; off >>= 1)
#pragma unroll
      for (int h = 0; h < 8; ++h) vm[h] = fmaxf(vm[h], __shfl_xor(vm[h], off, 64));
    if (lane == 0) {
#pragma unroll
      for (int h = 0; h < 8; ++h) redm[wid][h] = vm[h];
    }
    __syncthreads();
    if (tid < 8) {
      float m_old = mrun[tid];
      float cm = fmaxf(fmaxf(redm[0][tid], redm[1][tid]), fmaxf(redm[2][tid], redm[3][tid]));
      float m_new = fmaxf(m_old, cm);
      mrun[tid] = m_new;
      alpha[tid] = (m_old == -INFINITY) ? 0.f : __expf(m_old - m_new);
    }
    __syncthreads();
    float w[8];
#pragma unroll
    for (int h = 0; h < 8; ++h) {
      w[h] = __expf(e[h] - mrun[h]);  // e=-inf -> 0
      s_w[h][tid] = w[h];
    }
    s_idx[tid] = s;
    // wave sum-reduce
#pragma unroll
    for (int off = 32; off >= 1; off >>= 1)
#pragma unroll
      for (int h = 0; h < 8; ++h) w[h] += __shfl_xor(w[h], off, 64);
    if (lane == 0) {
#pragma unroll
      for (int h = 0; h < 8; ++h) reds[wid][h] = w[h];
    }
    __syncthreads();
    if (tid < 8) {
      float cs = reds[0][tid] + reds[1][tid] + reds[2][tid] + reds[3][tid];
      lrun[tid] = lrun[tid] * alpha[tid] + cs;
    }
    // phase B: coalesced gather-accumulate
    int cn = min(256, deg - c0);
    acc *= alpha[hh];
    const float* fh = f + (size_t)hh * 32 + dd;
    int jj = 0;
    for (; jj + 4 <= cn; jj += 4) {
      int s0 = s_idx[jj], s1 = s_idx[jj + 1], s2 = s_idx[jj + 2], s3 = s_idx[jj + 3];
      float w0 = s_w[hh][jj], w1 = s_w[hh][jj + 1], w2 = s_w[hh][jj + 2], w3 = s_w[hh][jj + 3];
      float v0 = fh[(size_t)s0 * 256], v1 = fh[(size_t)s1 * 256];
      float v2 = fh[(size_t)s2 * 256], v3 = fh[(size_t)s3 * 256];
      acc += v0 * w0 + v1 * w1 + v2 * w2 + v3 * w3;
    }
    for (; jj < cn; ++jj) {
      acc += fh[(size_t)s_idx[jj] * 256] * s_w[hh][jj];
    }
    __syncthreads();
  }

  float l = lrun[hh];
  float o = (deg > 0) ? (acc / l) : 0.f;
  o += b1[tid];
  o = (o > 0.f) ? o : (__expf(o) - 1.f);  // ELU
  hout[(size_t)node * 256 + tid] = o;
}

// ---------------- Layer 2 GEMM: f2 = h @ W2 (N x 256)@(256 x 32), + el2/er2 ----------------
__global__ __launch_bounds__(256) void k_gemm2(const float* __restrict__ h,
                                               const float* __restrict__ W2,
                                               const float* __restrict__ al2,
                                               const float* __restrict__ ar2,
                                               float* __restrict__ f2,
                                               float* __restrict__ el2,
                                               float* __restrict__ er2, int n) {
  int tid = threadIdx.x;
  int wave = tid >> 6, lane = tid & 63;
  int half = lane >> 5, c = lane & 31;
  int n0 = (blockIdx.x * 4 + wave) * 4;
  float acc[4] = {0.f, 0.f, 0.f, 0.f};
  float al_c = al2[c], ar_c = ar2[c];
  int k0 = half * 128;
  for (int k = k0; k < k0 + 128; ++k) {
    float w = W2[k * 32 + c];
#pragma unroll
    for (int i = 0; i < 4; ++i) {
      int nd = n0 + i;
      float hv = (nd < n) ? h[(size_t)nd * 256 + k] : 0.f;
      acc[i] += hv * w;
    }
  }
#pragma unroll
  for (int i = 0; i < 4; ++i) acc[i] += __shfl_xor(acc[i], 32, 64);
#pragma unroll
  for (int i = 0; i < 4; ++i) {
    int nd = n0 + i;
    float a = acc[i] * al_c, b = acc[i] * ar_c;
#pragma unroll
    for (int off = 16; off >= 1; off >>= 1) {
      a += __shfl_xor(a, off, 64);
      b += __shfl_xor(b, off, 64);
    }
    if (nd < n && half == 0) {
      f2[nd * 32 + c] = acc[i];
      if (c == 0) { el2[nd] = a; er2[nd] = b; }
    }
  }
}

// ---------------- Layer 2 aggregation -> output [N,32] ----------------
// one wave per dst node, 4 nodes per 256-block; shuffle-broadcast weights (no barriers)
__global__ __launch_bounds__(256) void k_agg2(const float* __restrict__ f2,
                                              const float* __restrict__ el2,
                                              const float* __restrict__ er2,
                                              const int* __restrict__ offsets,
                                              const int* __restrict__ counts,
                                              const int* __restrict__ csr_src,
                                              const float* __restrict__ b2,
                                              float* __restrict__ out, int n) {
  int wid = threadIdx.x >> 6, lane = threadIdx.x & 63;
  int node = blockIdx.x * 4 + wid;
  if (node >= n) return;
  int half = lane >> 5, d = lane & 31;
  int start = offsets[node], deg = counts[node];
  float erv = er2[node];
  float mrun = -INFINITY, lrun = 0.f, acc = 0.f;

  for (int c0 = 0; c0 < deg; c0 += 64) {
    int j = c0 + lane;
    float e = -INFINITY;
    int s = 0;
    if (j < deg) {
      s = csr_src[start + j];
      float v = el2[s] + erv;
      e = (v >= 0.f) ? v : NEG_SLOPE * v;
    }
    float cm = e;
#pragma unroll
    for (int off = 32; off >= 1; off >>= 1) cm = fmaxf(cm, __shfl_xor(cm, off, 64));
    float m_new = fmaxf(mrun, cm);
    float alpha = (mrun == -INFINITY) ? 0.f : __expf(mrun - m_new);
    mrun = m_new;
    float w = __expf(e - m_new);
    float cs = w;
#pragma unroll
    for (int off = 32; off >= 1; off >>= 1) cs += __shfl_xor(cs, off, 64);
    lrun = lrun * alpha + cs;
    acc *= alpha;
    int cn = min(64, deg - c0);
    for (int j2 = 0; j2 < cn; j2 += 2) {
      int jj = j2 + half;
      float wj = __shfl(w, jj, 64);
      int sj = __shfl(s, jj, 64);
      if (jj < cn) acc += f2[(size_t)sj * 32 + d] * wj;
    }
  }
  acc += __shfl_xor(acc, 32, 64);
  if (half == 0) {
    float o = (deg > 0) ? (acc / lrun) : 0.f;
    out[(size_t)node * 32 + d] = o + b2[d];
  }
}

// ---------------- launch ----------------

extern "C" void kernel_launch(void* const* d_in, const int* in_sizes, int n_in,
                              void* d_out, int out_size, void* d_ws, size_t ws_size,
                              hipStream_t stream) {
  const float* x   = (const float*)d_in[0];
  const int*   src = (const int*)d_in[1];
  const int*   dst = (const int*)d_in[2];
  const float* W1  = (const float*)d_in[3];
  const float* al1 = (const float*)d_in[4];
  const float* ar1 = (const float*)d_in[5];
  const float* b1  = (const float*)d_in[6];
  const float* W2  = (const float*)d_in[7];
  const float* al2 = (const float*)d_in[8];
  const float* ar2 = (const float*)d_in[9];
  const float* b2  = (const float*)d_in[10];
  float* out = (float*)d_out;

  int N = in_sizes[0] / 128;
  int E = in_sizes[1];

  char* w = (char*)d_ws;
  auto alloc = [&](size_t nelem) -> void* {
    void* p = (void*)w;
    w += ((nelem * 4 + 255) / 256) * 256;
    return p;
  };
  float* f1   = (float*)alloc((size_t)N * 256);
  float* h    = (float*)alloc((size_t)N * 256);
  float* el1  = (float*)alloc((size_t)N * 8);
  float* er1  = (float*)alloc((size_t)N * 8);
  float* f2   = (float*)alloc((size_t)N * 32);
  float* el2  = (float*)alloc(N);
  float* er2  = (float*)alloc(N);
  int* counts  = (int*)alloc(N);
  int* offsets = (int*)alloc(N);
  int* cursor  = (int*)alloc(N);
  int* csr_src = (int*)alloc(E);

  hipLaunchKernelGGL(k_zero_i32, dim3((N + 255) / 256), dim3(256), 0, stream, counts, N);
  hipLaunchKernelGGL(k_count, dim3((E + 255) / 256), dim3(256), 0, stream, dst, counts, E);
  hipLaunchKernelGGL(k_scan, dim3(1), dim3(1024), 0, stream, counts, offsets, cursor, N);
  hipLaunchKernelGGL(k_fill, dim3((E + 255) / 256), dim3(256), 0, stream, src, dst, cursor, csr_src, E);
  hipLaunchKernelGGL(k_gemm1, dim3((N + 63) / 64, 4), dim3(256), 0, stream, x, W1, f1, N);
  hipLaunchKernelGGL(k_attn1, dim3(N), dim3(256), 0, stream, f1, al1, ar1, el1, er1, N);
  hipLaunchKernelGGL(k_agg1, dim3(N), dim3(256), 0, stream, f1, el1, er1, offsets, counts, csr_src, b1, h, N);
  hipLaunchKernelGGL(k_gemm2, dim3((N + 15) / 16), dim3(256), 0, stream, h, W2, al2, ar2, f2, el2, er2, N);
  // 4 nodes per block (one wave each) -> grid = ceil(N/4)
  hipLaunchKernelGGL(k_agg2, dim3((N + 3) / 4), dim3(256), 0, stream, f2, el2, er2, offsets, counts, csr_src, b2, out, N);
}

// Round 4
// 509.180 us; speedup vs baseline: 1.4773x; 1.2429x over previous
//
#include <hip/hip_runtime.h>
#include <math.h>

#define NEG_SLOPE 0.2f

// ---------------- CSR build ----------------

__global__ void k_zero_i32(int* __restrict__ p, int n) {
  int i = blockIdx.x * 256 + threadIdx.x;
  if (i < n) p[i] = 0;
}

__global__ void k_count(const int* __restrict__ dst, int* __restrict__ counts, int E) {
  int i = blockIdx.x * 256 + threadIdx.x;
  if (i < E) atomicAdd(&counts[dst[i]], 1);
}

// single-block exclusive scan over counts[0..n) -> offsets, cursor
__global__ __launch_bounds__(1024) void k_scan(const int* __restrict__ counts,
                                               int* __restrict__ offsets,
                                               int* __restrict__ cursor, int n) {
  __shared__ int wsum[16];
  int tid = threadIdx.x;
  int lane = tid & 63, wid = tid >> 6;
  int carry = 0;
  for (int base = 0; base < n; base += 1024) {
    int i = base + tid;
    int v = (i < n) ? counts[i] : 0;
    int orig = v;
#pragma unroll
    for (int off = 1; off < 64; off <<= 1) {
      int u = __shfl_up(v, off, 64);
      if (lane >= off) v += u;
    }
    if (lane == 63) wsum[wid] = v;
    __syncthreads();
    if (wid == 0 && lane < 16) {
      int s = wsum[lane];
#pragma unroll
      for (int off = 1; off < 16; off <<= 1) {
        int u = __shfl_up(s, off, 64);
        if (lane >= off) s += u;
      }
      wsum[lane] = s;
    }
    __syncthreads();
    int wbase = (wid > 0) ? wsum[wid - 1] : 0;
    int tot = wsum[15];
    int excl = carry + wbase + (v - orig);
    if (i < n) { offsets[i] = excl; cursor[i] = excl; }
    carry += tot;
    __syncthreads();
  }
}

__global__ void k_fill(const int* __restrict__ src, const int* __restrict__ dst,
                       int* __restrict__ cursor, int* __restrict__ csr_src,
                       int* __restrict__ csr_dst, int E) {
  int i = blockIdx.x * 256 + threadIdx.x;
  if (i < E) {
    int d = dst[i];
    int pos = atomicAdd(&cursor[d], 1);
    csr_src[pos] = src[i];
    csr_dst[pos] = d;
  }
}

// ---------------- Layer 1 GEMM: f1 = x @ W1  (N x 128) @ (128 x 256) ----------------
__global__ __launch_bounds__(256) void k_gemm1(const float* __restrict__ x,
                                               const float* __restrict__ W,
                                               float* __restrict__ f, int n) {
  __shared__ __align__(16) float xs[32][64];  // [k][node]
  __shared__ __align__(16) float ws[32][64];  // [k][col]
  int tid = threadIdx.x;
  int tm = tid >> 4, tn = tid & 15;
  int m0 = blockIdx.x * 64;
  int c0 = blockIdx.y * 64;
  float acc[4][4];
#pragma unroll
  for (int i = 0; i < 4; ++i)
#pragma unroll
    for (int j = 0; j < 4; ++j) acc[i][j] = 0.f;

  for (int kb = 0; kb < 128; kb += 32) {
#pragma unroll
    for (int r = 0; r < 2; ++r) {
      int e = tid * 8 + r * 4;
      int node = e >> 5, kk = e & 31;
      float4 v = make_float4(0.f, 0.f, 0.f, 0.f);
      int gn = m0 + node;
      if (gn < n) v = *(const float4*)(x + (size_t)gn * 128 + kb + kk);
      xs[kk + 0][node] = v.x; xs[kk + 1][node] = v.y;
      xs[kk + 2][node] = v.z; xs[kk + 3][node] = v.w;
      int kw = e >> 6, cc = e & 63;
      *(float4*)(&ws[kw][cc]) = *(const float4*)(W + (size_t)(kb + kw) * 256 + c0 + cc);
    }
    __syncthreads();
#pragma unroll
    for (int k = 0; k < 32; ++k) {
      float4 a = *(float4*)(&xs[k][tm * 4]);
      float4 b = *(float4*)(&ws[k][tn * 4]);
      acc[0][0] += a.x * b.x; acc[0][1] += a.x * b.y; acc[0][2] += a.x * b.z; acc[0][3] += a.x * b.w;
      acc[1][0] += a.y * b.x; acc[1][1] += a.y * b.y; acc[1][2] += a.y * b.z; acc[1][3] += a.y * b.w;
      acc[2][0] += a.z * b.x; acc[2][1] += a.z * b.y; acc[2][2] += a.z * b.z; acc[2][3] += a.z * b.w;
      acc[3][0] += a.w * b.x; acc[3][1] += a.w * b.y; acc[3][2] += a.w * b.z; acc[3][3] += a.w * b.w;
    }
    __syncthreads();
  }
#pragma unroll
  for (int i = 0; i < 4; ++i) {
    int gn = m0 + tm * 4 + i;
    if (gn < n) {
      float4 v = make_float4(acc[i][0], acc[i][1], acc[i][2], acc[i][3]);
      *(float4*)(&f[(size_t)gn * 256 + c0 + tn * 4]) = v;
    }
  }
}

// ---------------- Layer 1 attention logits: el1/er1 [N,8] ----------------
__global__ __launch_bounds__(256) void k_attn1(const float* __restrict__ f,
                                               const float* __restrict__ al,
                                               const float* __restrict__ ar,
                                               float* __restrict__ el, float* __restrict__ er,
                                               int n) {
  int tid = threadIdx.x;
  int g = tid >> 5, lane32 = tid & 31;
  int gid = blockIdx.x * 8 + g;
  int node = gid >> 3, hh = gid & 7;
  float v = f[(size_t)node * 256 + hh * 32 + lane32];
  float a = v * al[hh * 32 + lane32];
  float b = v * ar[hh * 32 + lane32];
#pragma unroll
  for (int off = 16; off >= 1; off >>= 1) {
    a += __shfl_xor(a, off, 64);
    b += __shfl_xor(b, off, 64);
  }
  if (lane32 == 0) { el[node * 8 + hh] = a; er[node * 8 + hh] = b; }
}

// ---------------- Layer 1 edge weights (no max-sub; logits are O(1), exp safe) ----------------
__global__ __launch_bounds__(256) void k_edgew1(const float* __restrict__ el,
                                                const float* __restrict__ er,
                                                const int* __restrict__ csr_src,
                                                const int* __restrict__ csr_dst,
                                                float* __restrict__ we, int E) {
  int p = blockIdx.x * 256 + threadIdx.x;
  if (p >= E) return;
  int s = csr_src[p], d = csr_dst[p];
  float4 a0 = *(const float4*)(el + (size_t)s * 8);
  float4 a1 = *(const float4*)(el + (size_t)s * 8 + 4);
  float4 r0 = *(const float4*)(er + (size_t)d * 8);
  float4 r1 = *(const float4*)(er + (size_t)d * 8 + 4);
  float e[8] = {a0.x + r0.x, a0.y + r0.y, a0.z + r0.z, a0.w + r0.w,
                a1.x + r1.x, a1.y + r1.y, a1.z + r1.z, a1.w + r1.w};
  float w[8];
#pragma unroll
  for (int h = 0; h < 8; ++h) {
    float v = e[h];
    v = (v >= 0.f) ? v : NEG_SLOPE * v;
    w[h] = __expf(v);
  }
  float4* o = (float4*)(we + (size_t)p * 8);
  o[0] = make_float4(w[0], w[1], w[2], w[3]);
  o[1] = make_float4(w[4], w[5], w[6], w[7]);
}

// ---------------- Layer 1 aggregation: pure weighted gather ----------------
// block per node; wave q handles edges q, q+4, ...; lane l covers dims 4l..4l+3.
__global__ __launch_bounds__(256) void k_agg1(const float4* __restrict__ f4,
                                              const float* __restrict__ we,
                                              const int* __restrict__ offsets,
                                              const int* __restrict__ counts,
                                              const int* __restrict__ csr_src,
                                              const float4* __restrict__ b1_4,
                                              float4* __restrict__ hout4, int n) {
  const int node = blockIdx.x;
  const int tid = threadIdx.x;
  const int q = tid >> 6, l = tid & 63;
  const int h = l >> 3;
  __shared__ __align__(16) float4 s_acc[4][64];
  __shared__ float s_dw[4][64];

  int start = offsets[node], deg = counts[node];
  float4 acc = make_float4(0.f, 0.f, 0.f, 0.f);
  float dw = 0.f;

  int j = q;
  int sN = (j < deg) ? csr_src[start + j] : 0;
  while (j < deg) {
    int s = sN;
    int j2 = j + 4;
    sN = (j2 < deg) ? csr_src[start + j2] : 0;
    float w = we[(size_t)(start + j) * 8 + h];
    float4 v = f4[(size_t)s * 64 + l];
    acc.x += w * v.x; acc.y += w * v.y; acc.z += w * v.z; acc.w += w * v.w;
    dw += w;
    j = j2;
  }
  s_acc[q][l] = acc;
  s_dw[q][l] = dw;
  __syncthreads();
  if (tid < 64) {
    float4 a0 = s_acc[0][l], a1 = s_acc[1][l], a2 = s_acc[2][l], a3 = s_acc[3][l];
    float denom = s_dw[0][l] + s_dw[1][l] + s_dw[2][l] + s_dw[3][l];
    float inv = (deg > 0) ? 1.f / denom : 0.f;
    float4 b = b1_4[l];
    float4 r;
    r.x = (a0.x + a1.x + a2.x + a3.x) * inv + b.x;
    r.y = (a0.y + a1.y + a2.y + a3.y) * inv + b.y;
    r.z = (a0.z + a1.z + a2.z + a3.z) * inv + b.z;
    r.w = (a0.w + a1.w + a2.w + a3.w) * inv + b.w;
    r.x = (r.x > 0.f) ? r.x : (__expf(r.x) - 1.f);
    r.y = (r.y > 0.f) ? r.y : (__expf(r.y) - 1.f);
    r.z = (r.z > 0.f) ? r.z : (__expf(r.z) - 1.f);
    r.w = (r.w > 0.f) ? r.w : (__expf(r.w) - 1.f);
    hout4[(size_t)node * 64 + l] = r;
  }
}

// ---------------- Layer 2 GEMM: f2 = h @ W2 (N x 256)@(256 x 32), + el2/er2 ----------------
__global__ __launch_bounds__(256) void k_gemm2(const float* __restrict__ h,
                                               const float* __restrict__ W2,
                                               const float* __restrict__ al2,
                                               const float* __restrict__ ar2,
                                               float* __restrict__ f2,
                                               float* __restrict__ el2,
                                               float* __restrict__ er2, int n) {
  int tid = threadIdx.x;
  int wave = tid >> 6, lane = tid & 63;
  int half = lane >> 5, c = lane & 31;
  int n0 = (blockIdx.x * 4 + wave) * 4;
  float acc[4] = {0.f, 0.f, 0.f, 0.f};
  float al_c = al2[c], ar_c = ar2[c];
  int k0 = half * 128;
  for (int k = k0; k < k0 + 128; ++k) {
    float w = W2[k * 32 + c];
#pragma unroll
    for (int i = 0; i < 4; ++i) {
      int nd = n0 + i;
      float hv = (nd < n) ? h[(size_t)nd * 256 + k] : 0.f;
      acc[i] += hv * w;
    }
  }
#pragma unroll
  for (int i = 0; i < 4; ++i) acc[i] += __shfl_xor(acc[i], 32, 64);
#pragma unroll
  for (int i = 0; i < 4; ++i) {
    int nd = n0 + i;
    float a = acc[i] * al_c, b = acc[i] * ar_c;
#pragma unroll
    for (int off = 16; off >= 1; off >>= 1) {
      a += __shfl_xor(a, off, 64);
      b += __shfl_xor(b, off, 64);
    }
    if (nd < n && half == 0) {
      f2[nd * 32 + c] = acc[i];
      if (c == 0) { el2[nd] = a; er2[nd] = b; }
    }
  }
}

// ---------------- Layer 2 edge weights ----------------
__global__ __launch_bounds__(256) void k_edgew2(const float* __restrict__ el2,
                                                const float* __restrict__ er2,
                                                const int* __restrict__ csr_src,
                                                const int* __restrict__ csr_dst,
                                                float* __restrict__ w2, int E) {
  int p = blockIdx.x * 256 + threadIdx.x;
  if (p >= E) return;
  int s = csr_src[p], d = csr_dst[p];
  float v = el2[s] + er2[d];
  v = (v >= 0.f) ? v : NEG_SLOPE * v;
  w2[p] = __expf(v);
}

// ---------------- Layer 2 aggregation -> output [N,32] ----------------
// one wave per node; lane: edge-group eg=l>>3 (8 edges in flight), d4=l&7 covers dims 4*d4..
__global__ __launch_bounds__(256) void k_agg2(const float4* __restrict__ f2_4,
                                              const float* __restrict__ w2,
                                              const int* __restrict__ offsets,
                                              const int* __restrict__ counts,
                                              const int* __restrict__ csr_src,
                                              const float4* __restrict__ b2_4,
                                              float4* __restrict__ out4, int n) {
  int wid = threadIdx.x >> 6, lane = threadIdx.x & 63;
  int node = blockIdx.x * 4 + wid;
  if (node >= n) return;
  int eg = lane >> 3, d4 = lane & 7;
  int start = offsets[node], deg = counts[node];
  float4 acc = make_float4(0.f, 0.f, 0.f, 0.f);
  float dw = 0.f;
  int j = eg;
  int sN = (j < deg) ? csr_src[start + j] : 0;
  while (j < deg) {
    int s = sN;
    int j2 = j + 8;
    sN = (j2 < deg) ? csr_src[start + j2] : 0;
    float w = w2[start + j];
    float4 v = f2_4[(size_t)s * 8 + d4];
    acc.x += w * v.x; acc.y += w * v.y; acc.z += w * v.z; acc.w += w * v.w;
    dw += w;
    j = j2;
  }
#pragma unroll
  for (int off = 8; off <= 32; off <<= 1) {
    acc.x += __shfl_xor(acc.x, off, 64);
    acc.y += __shfl_xor(acc.y, off, 64);
    acc.z += __shfl_xor(acc.z, off, 64);
    acc.w += __shfl_xor(acc.w, off, 64);
    dw += __shfl_xor(dw, off, 64);
  }
  if (eg == 0) {
    float inv = (deg > 0) ? 1.f / dw : 0.f;
    float4 b = b2_4[d4];
    float4 r;
    r.x = acc.x * inv + b.x;
    r.y = acc.y * inv + b.y;
    r.z = acc.z * inv + b.z;
    r.w = acc.w * inv + b.w;
    out4[(size_t)node * 8 + d4] = r;
  }
}

// ---------------- launch ----------------

extern "C" void kernel_launch(void* const* d_in, const int* in_sizes, int n_in,
                              void* d_out, int out_size, void* d_ws, size_t ws_size,
                              hipStream_t stream) {
  const float* x   = (const float*)d_in[0];
  const int*   src = (const int*)d_in[1];
  const int*   dst = (const int*)d_in[2];
  const float* W1  = (const float*)d_in[3];
  const float* al1 = (const float*)d_in[4];
  const float* ar1 = (const float*)d_in[5];
  const float* b1  = (const float*)d_in[6];
  const float* W2  = (const float*)d_in[7];
  const float* al2 = (const float*)d_in[8];
  const float* ar2 = (const float*)d_in[9];
  const float* b2  = (const float*)d_in[10];
  float* out = (float*)d_out;

  int N = in_sizes[0] / 128;
  int E = in_sizes[1];

  char* w = (char*)d_ws;
  auto alloc = [&](size_t nelem) -> void* {
    void* p = (void*)w;
    w += ((nelem * 4 + 255) / 256) * 256;
    return p;
  };
  float* f1   = (float*)alloc((size_t)N * 256);
  float* h    = (float*)alloc((size_t)N * 256);
  float* el1  = (float*)alloc((size_t)N * 8);
  float* er1  = (float*)alloc((size_t)N * 8);
  float* f2   = (float*)alloc((size_t)N * 32);
  float* el2  = (float*)alloc(N);
  float* er2  = (float*)alloc(N);
  int* counts  = (int*)alloc(N);
  int* offsets = (int*)alloc(N);
  int* cursor  = (int*)alloc(N);
  int* csr_src = (int*)alloc(E);
  int* csr_dst = (int*)alloc(E);
  float* we1   = (float*)alloc((size_t)E * 8);
  float* w2e   = (float*)alloc(E);

  hipLaunchKernelGGL(k_zero_i32, dim3((N + 255) / 256), dim3(256), 0, stream, counts, N);
  hipLaunchKernelGGL(k_count, dim3((E + 255) / 256), dim3(256), 0, stream, dst, counts, E);
  hipLaunchKernelGGL(k_scan, dim3(1), dim3(1024), 0, stream, counts, offsets, cursor, N);
  hipLaunchKernelGGL(k_fill, dim3((E + 255) / 256), dim3(256), 0, stream, src, dst, cursor, csr_src, csr_dst, E);
  hipLaunchKernelGGL(k_gemm1, dim3((N + 63) / 64, 4), dim3(256), 0, stream, x, W1, f1, N);
  hipLaunchKernelGGL(k_attn1, dim3(N), dim3(256), 0, stream, f1, al1, ar1, el1, er1, N);
  hipLaunchKernelGGL(k_edgew1, dim3((E + 255) / 256), dim3(256), 0, stream, el1, er1, csr_src, csr_dst, we1, E);
  hipLaunchKernelGGL(k_agg1, dim3(N), dim3(256), 0, stream, (const float4*)f1, we1, offsets, counts, csr_src,
                     (const float4*)b1, (float4*)h, N);
  hipLaunchKernelGGL(k_gemm2, dim3((N + 15) / 16), dim3(256), 0, stream, h, W2, al2, ar2, f2, el2, er2, N);
  hipLaunchKernelGGL(k_edgew2, dim3((E + 255) / 256), dim3(256), 0, stream, el2, er2, csr_src, csr_dst, w2e, E);
  hipLaunchKernelGGL(k_agg2, dim3((N + 3) / 4), dim3(256), 0, stream, (const float4*)f2, w2e, offsets, counts,
                     csr_src, (const float4*)b2, (float4*)out, N);
}

// Round 5
// 421.983 us; speedup vs baseline: 1.7826x; 1.2066x over previous
//
#include <hip/hip_runtime.h>
#include <math.h>

#define NEG_SLOPE 0.2f

__device__ inline unsigned short f2bf(float x) {
  unsigned u = __float_as_uint(x);
  u += 0x7fffu + ((u >> 16) & 1u);  // RNE
  return (unsigned short)(u >> 16);
}
__device__ inline float bf2f(unsigned short b) {
  return __uint_as_float(((unsigned)b) << 16);
}

// ---------------- CSR build ----------------

__global__ void k_zero2(int* __restrict__ counts, int n, int* __restrict__ total) {
  int i = blockIdx.x * 256 + threadIdx.x;
  if (i < n) counts[i] = 0;
  if (i == 0) *total = 0;
}

__global__ void k_count(const int* __restrict__ dst, int* __restrict__ counts, int E) {
  int i = blockIdx.x * 256 + threadIdx.x;
  if (i < E) atomicAdd(&counts[dst[i]], 1);
}

// offsets = disjoint contiguous ranges (order irrelevant: aggregation is commutative)
__global__ void k_offsets(const int* __restrict__ counts, int* __restrict__ offsets,
                          int* __restrict__ cursor, int* __restrict__ total, int n) {
  int i = blockIdx.x * 256 + threadIdx.x;
  if (i < n) {
    int c = counts[i];
    int o = atomicAdd(total, c);
    offsets[i] = o;
    cursor[i] = o;
  }
}

__global__ void k_fill(const int* __restrict__ src, const int* __restrict__ dst,
                       int* __restrict__ cursor, int* __restrict__ csr_src, int E) {
  int i = blockIdx.x * 256 + threadIdx.x;
  if (i < E) {
    int d = dst[i];
    int pos = atomicAdd(&cursor[d], 1);
    csr_src[pos] = src[i];
  }
}

// ---------------- Layer 1 GEMM + fused attention logits ----------------
// f1b (bf16) = x @ W1; el/er computed from fp32 accumulators in-epilogue.
// grid: (ceil(N/64), 4); block col-range = 64 cols = 2 heads.
__global__ __launch_bounds__(256) void k_gemm1(const float* __restrict__ x,
                                               const float* __restrict__ W,
                                               const float* __restrict__ al,
                                               const float* __restrict__ ar,
                                               unsigned short* __restrict__ f1b,
                                               float* __restrict__ el,
                                               float* __restrict__ er, int n) {
  __shared__ __align__(16) float xs[32][64];  // [k][node]
  __shared__ __align__(16) float ws[32][64];  // [k][col]
  int tid = threadIdx.x;
  int tm = tid >> 4, tn = tid & 15;
  int m0 = blockIdx.x * 64;
  int c0 = blockIdx.y * 64;
  float acc[4][4];
#pragma unroll
  for (int i = 0; i < 4; ++i)
#pragma unroll
    for (int j = 0; j < 4; ++j) acc[i][j] = 0.f;

  for (int kb = 0; kb < 128; kb += 32) {
#pragma unroll
    for (int r = 0; r < 2; ++r) {
      int e = tid * 8 + r * 4;
      int node = e >> 5, kk = e & 31;
      float4 v = make_float4(0.f, 0.f, 0.f, 0.f);
      int gn = m0 + node;
      if (gn < n) v = *(const float4*)(x + (size_t)gn * 128 + kb + kk);
      xs[kk + 0][node] = v.x; xs[kk + 1][node] = v.y;
      xs[kk + 2][node] = v.z; xs[kk + 3][node] = v.w;
      int kw = e >> 6, cc = e & 63;
      *(float4*)(&ws[kw][cc]) = *(const float4*)(W + (size_t)(kb + kw) * 256 + c0 + cc);
    }
    __syncthreads();
#pragma unroll
    for (int k = 0; k < 32; ++k) {
      float4 a = *(float4*)(&xs[k][tm * 4]);
      float4 b = *(float4*)(&ws[k][tn * 4]);
      acc[0][0] += a.x * b.x; acc[0][1] += a.x * b.y; acc[0][2] += a.x * b.z; acc[0][3] += a.x * b.w;
      acc[1][0] += a.y * b.x; acc[1][1] += a.y * b.y; acc[1][2] += a.y * b.z; acc[1][3] += a.y * b.w;
      acc[2][0] += a.z * b.x; acc[2][1] += a.z * b.y; acc[2][2] += a.z * b.z; acc[2][3] += a.z * b.w;
      acc[3][0] += a.w * b.x; acc[3][1] += a.w * b.y; acc[3][2] += a.w * b.z; acc[3][3] += a.w * b.w;
    }
    __syncthreads();
  }

  const int c_base = c0 + tn * 4;              // 4 cols, all within one head (32-dim)
  const int head = (c_base >> 5) & 7;
  float4 alv = *(const float4*)(al + c_base);
  float4 arv = *(const float4*)(ar + c_base);
#pragma unroll
  for (int i = 0; i < 4; ++i) {
    int gn = m0 + tm * 4 + i;
    bool valid = gn < n;
    float4 a = make_float4(acc[i][0], acc[i][1], acc[i][2], acc[i][3]);
    if (valid) {
      ushort4 pk;
      pk.x = f2bf(a.x); pk.y = f2bf(a.y); pk.z = f2bf(a.z); pk.w = f2bf(a.w);
      *(ushort4*)(f1b + (size_t)gn * 256 + c_base) = pk;
    }
    float pel = a.x * alv.x + a.y * alv.y + a.z * alv.z + a.w * alv.w;
    float per = a.x * arv.x + a.y * arv.y + a.z * arv.z + a.w * arv.w;
#pragma unroll
    for (int off = 1; off < 8; off <<= 1) {   // reduce 8 lanes covering the head's 32 dims
      pel += __shfl_xor(pel, off, 64);
      per += __shfl_xor(per, off, 64);
    }
    if (valid && (tn & 7) == 0) {
      el[gn * 8 + head] = pel;
      er[gn * 8 + head] = per;
    }
  }
}

// ---------------- Layer 1 aggregation: fused edge weights + bf16 gather ----------------
// block per node; wave q handles edges q, q+4, ...; lane l covers dims 4l..4l+3 (head = l>>3).
__global__ __launch_bounds__(256) void k_agg1(const unsigned short* __restrict__ f1b,
                                              const float* __restrict__ el,
                                              const float* __restrict__ er,
                                              const int* __restrict__ offsets,
                                              const int* __restrict__ counts,
                                              const int* __restrict__ csr_src,
                                              const float4* __restrict__ b1_4,
                                              float4* __restrict__ hout4, int n) {
  const int node = blockIdx.x;
  const int tid = threadIdx.x;
  const int q = tid >> 6, l = tid & 63;
  const int h = l >> 3;
  __shared__ __align__(16) float4 s_acc[4][64];
  __shared__ float s_dw[4][64];

  int start = offsets[node], deg = counts[node];
  float er0 = er[node * 8 + h];
  float4 acc = make_float4(0.f, 0.f, 0.f, 0.f);
  float dw = 0.f;

  int j = q;
  int sN = (j < deg) ? csr_src[start + j] : 0;
  while (j < deg) {
    int s = sN;
    int j2 = j + 4;
    sN = (j2 < deg) ? csr_src[start + j2] : 0;
    float ev = el[(size_t)s * 8 + h] + er0;
    ev = (ev >= 0.f) ? ev : NEG_SLOPE * ev;
    float w = __expf(ev);
    ushort4 vb = *(const ushort4*)(f1b + (size_t)s * 256 + l * 4);
    acc.x += w * bf2f(vb.x); acc.y += w * bf2f(vb.y);
    acc.z += w * bf2f(vb.z); acc.w += w * bf2f(vb.w);
    dw += w;
    j = j2;
  }
  s_acc[q][l] = acc;
  s_dw[q][l] = dw;
  __syncthreads();
  if (tid < 64) {
    float4 a0 = s_acc[0][l], a1 = s_acc[1][l], a2 = s_acc[2][l], a3 = s_acc[3][l];
    float denom = s_dw[0][l] + s_dw[1][l] + s_dw[2][l] + s_dw[3][l];
    float inv = (deg > 0) ? 1.f / denom : 0.f;
    float4 b = b1_4[l];
    float4 r;
    r.x = (a0.x + a1.x + a2.x + a3.x) * inv + b.x;
    r.y = (a0.y + a1.y + a2.y + a3.y) * inv + b.y;
    r.z = (a0.z + a1.z + a2.z + a3.z) * inv + b.z;
    r.w = (a0.w + a1.w + a2.w + a3.w) * inv + b.w;
    r.x = (r.x > 0.f) ? r.x : (__expf(r.x) - 1.f);
    r.y = (r.y > 0.f) ? r.y : (__expf(r.y) - 1.f);
    r.z = (r.z > 0.f) ? r.z : (__expf(r.z) - 1.f);
    r.w = (r.w > 0.f) ? r.w : (__expf(r.w) - 1.f);
    hout4[(size_t)node * 64 + l] = r;
  }
}

// ---------------- Layer 2 GEMM: f2 = h @ W2 (N x 256)@(256 x 32), + el2/er2 ----------------
__global__ __launch_bounds__(256) void k_gemm2(const float* __restrict__ h,
                                               const float* __restrict__ W2,
                                               const float* __restrict__ al2,
                                               const float* __restrict__ ar2,
                                               float* __restrict__ f2,
                                               float* __restrict__ el2,
                                               float* __restrict__ er2, int n) {
  int tid = threadIdx.x;
  int wave = tid >> 6, lane = tid & 63;
  int half = lane >> 5, c = lane & 31;
  int n0 = (blockIdx.x * 4 + wave) * 4;
  float acc[4] = {0.f, 0.f, 0.f, 0.f};
  float al_c = al2[c], ar_c = ar2[c];
  int k0 = half * 128;
  for (int k = k0; k < k0 + 128; ++k) {
    float w = W2[k * 32 + c];
#pragma unroll
    for (int i = 0; i < 4; ++i) {
      int nd = n0 + i;
      float hv = (nd < n) ? h[(size_t)nd * 256 + k] : 0.f;
      acc[i] += hv * w;
    }
  }
#pragma unroll
  for (int i = 0; i < 4; ++i) acc[i] += __shfl_xor(acc[i], 32, 64);
#pragma unroll
  for (int i = 0; i < 4; ++i) {
    int nd = n0 + i;
    float a = acc[i] * al_c, b = acc[i] * ar_c;
#pragma unroll
    for (int off = 16; off >= 1; off >>= 1) {
      a += __shfl_xor(a, off, 64);
      b += __shfl_xor(b, off, 64);
    }
    if (nd < n && half == 0) {
      f2[nd * 32 + c] = acc[i];
      if (c == 0) { el2[nd] = a; er2[nd] = b; }
    }
  }
}

// ---------------- Layer 2 aggregation (fused edge weights) -> output [N,32] ----------------
// one wave per node; eg=l>>3 (8 edges in flight), d4=l&7 covers dims 4*d4..4*d4+3
__global__ __launch_bounds__(256) void k_agg2(const float4* __restrict__ f2_4,
                                              const float* __restrict__ el2,
                                              const float* __restrict__ er2,
                                              const int* __restrict__ offsets,
                                              const int* __restrict__ counts,
                                              const int* __restrict__ csr_src,
                                              const float4* __restrict__ b2_4,
                                              float4* __restrict__ out4, int n) {
  int wid = threadIdx.x >> 6, lane = threadIdx.x & 63;
  int node = blockIdx.x * 4 + wid;
  if (node >= n) return;
  int eg = lane >> 3, d4 = lane & 7;
  int start = offsets[node], deg = counts[node];
  float er0 = er2[node];
  float4 acc = make_float4(0.f, 0.f, 0.f, 0.f);
  float dw = 0.f;
  int j = eg;
  int sN = (j < deg) ? csr_src[start + j] : 0;
  while (j < deg) {
    int s = sN;
    int j2 = j + 8;
    sN = (j2 < deg) ? csr_src[start + j2] : 0;
    float ev = el2[s] + er0;
    ev = (ev >= 0.f) ? ev : NEG_SLOPE * ev;
    float w = __expf(ev);
    float4 v = f2_4[(size_t)s * 8 + d4];
    acc.x += w * v.x; acc.y += w * v.y; acc.z += w * v.z; acc.w += w * v.w;
    dw += w;
    j = j2;
  }
#pragma unroll
  for (int off = 8; off <= 32; off <<= 1) {
    acc.x += __shfl_xor(acc.x, off, 64);
    acc.y += __shfl_xor(acc.y, off, 64);
    acc.z += __shfl_xor(acc.z, off, 64);
    acc.w += __shfl_xor(acc.w, off, 64);
    dw += __shfl_xor(dw, off, 64);
  }
  if (eg == 0) {
    float inv = (deg > 0) ? 1.f / dw : 0.f;
    float4 b = b2_4[d4];
    float4 r;
    r.x = acc.x * inv + b.x;
    r.y = acc.y * inv + b.y;
    r.z = acc.z * inv + b.z;
    r.w = acc.w * inv + b.w;
    out4[(size_t)node * 8 + d4] = r;
  }
}

// ---------------- launch ----------------

extern "C" void kernel_launch(void* const* d_in, const int* in_sizes, int n_in,
                              void* d_out, int out_size, void* d_ws, size_t ws_size,
                              hipStream_t stream) {
  const float* x   = (const float*)d_in[0];
  const int*   src = (const int*)d_in[1];
  const int*   dst = (const int*)d_in[2];
  const float* W1  = (const float*)d_in[3];
  const float* al1 = (const float*)d_in[4];
  const float* ar1 = (const float*)d_in[5];
  const float* b1  = (const float*)d_in[6];
  const float* W2  = (const float*)d_in[7];
  const float* al2 = (const float*)d_in[8];
  const float* ar2 = (const float*)d_in[9];
  const float* b2  = (const float*)d_in[10];
  float* out = (float*)d_out;

  int N = in_sizes[0] / 128;
  int E = in_sizes[1];

  char* w = (char*)d_ws;
  auto alloc = [&](size_t nbytes) -> void* {
    void* p = (void*)w;
    w += ((nbytes + 255) / 256) * 256;
    return p;
  };
  unsigned short* f1b = (unsigned short*)alloc((size_t)N * 256 * 2);
  float* h    = (float*)alloc((size_t)N * 256 * 4);
  float* el1  = (float*)alloc((size_t)N * 8 * 4);
  float* er1  = (float*)alloc((size_t)N * 8 * 4);
  float* f2   = (float*)alloc((size_t)N * 32 * 4);
  float* el2  = (float*)alloc((size_t)N * 4);
  float* er2  = (float*)alloc((size_t)N * 4);
  int* counts  = (int*)alloc((size_t)N * 4);
  int* offsets = (int*)alloc((size_t)N * 4);
  int* cursor  = (int*)alloc((size_t)N * 4);
  int* total   = (int*)alloc(4);
  int* csr_src = (int*)alloc((size_t)E * 4);

  hipLaunchKernelGGL(k_zero2, dim3((N + 255) / 256), dim3(256), 0, stream, counts, N, total);
  hipLaunchKernelGGL(k_count, dim3((E + 255) / 256), dim3(256), 0, stream, dst, counts, E);
  hipLaunchKernelGGL(k_offsets, dim3((N + 255) / 256), dim3(256), 0, stream, counts, offsets, cursor, total, N);
  hipLaunchKernelGGL(k_fill, dim3((E + 255) / 256), dim3(256), 0, stream, src, dst, cursor, csr_src, E);
  hipLaunchKernelGGL(k_gemm1, dim3((N + 63) / 64, 4), dim3(256), 0, stream, x, W1, al1, ar1, f1b, el1, er1, N);
  hipLaunchKernelGGL(k_agg1, dim3(N), dim3(256), 0, stream, f1b, el1, er1, offsets, counts, csr_src,
                     (const float4*)b1, (float4*)h, N);
  hipLaunchKernelGGL(k_gemm2, dim3((N + 15) / 16), dim3(256), 0, stream, h, W2, al2, ar2, f2, el2, er2, N);
  hipLaunchKernelGGL(k_agg2, dim3((N + 3) / 4), dim3(256), 0, stream, (const float4*)f2, el2, er2, offsets,
                     counts, csr_src, (const float4*)b2, (float4*)out, N);
}

// Round 6
// 313.538 us; speedup vs baseline: 2.3992x; 1.3459x over previous
//
#include <hip/hip_runtime.h>
#include <math.h>

#define NEG_SLOPE 0.2f

typedef short v8s __attribute__((ext_vector_type(8)));   // 8 bf16 in 4 VGPRs
typedef float v4f __attribute__((ext_vector_type(4)));

__device__ inline unsigned short f2bf(float x) {
  unsigned u = __float_as_uint(x);
  u += 0x7fffu + ((u >> 16) & 1u);  // RNE
  return (unsigned short)(u >> 16);
}

// ---------------- CSR build ----------------

__global__ void k_zero2(int* __restrict__ counts, int n, int* __restrict__ total) {
  int i = blockIdx.x * 256 + threadIdx.x;
  if (i < n) counts[i] = 0;
  if (i == 0) *total = 0;
}

__global__ void k_count(const int* __restrict__ dst, int* __restrict__ counts, int E) {
  int i = blockIdx.x * 256 + threadIdx.x;
  if (i < E) atomicAdd(&counts[dst[i]], 1);
}

__global__ void k_offsets(const int* __restrict__ counts, int* __restrict__ offsets,
                          int* __restrict__ cursor, int* __restrict__ total, int n) {
  int i = blockIdx.x * 256 + threadIdx.x;
  if (i < n) {
    int c = counts[i];
    int o = atomicAdd(total, c);
    offsets[i] = o;
    cursor[i] = o;
  }
}

__global__ void k_fill(const int* __restrict__ src, const int* __restrict__ dst,
                       int* __restrict__ cursor, int* __restrict__ csr_src, int E) {
  int i = blockIdx.x * 256 + threadIdx.x;
  if (i < E) {
    int d = dst[i];
    int pos = atomicAdd(&cursor[d], 1);
    csr_src[pos] = src[i];
  }
}

// ---------------- prep: x -> bf16, W1/W2 -> transposed bf16 ----------------

__global__ void k_castx(const float4* __restrict__ x4, ushort4* __restrict__ xb4, int n4) {
  int i = blockIdx.x * 256 + threadIdx.x;
  if (i >= n4) return;
  float4 v = x4[i];
  ushort4 o;
  o.x = f2bf(v.x); o.y = f2bf(v.y); o.z = f2bf(v.z); o.w = f2bf(v.w);
  xb4[i] = o;
}

__global__ void k_prepW(const float* __restrict__ W1, const float* __restrict__ W2,
                        unsigned short* __restrict__ W1T, unsigned short* __restrict__ W2T) {
  int gid = blockIdx.x * 256 + threadIdx.x;
  if (gid < 32768) {
    int k = gid & 127, nn = gid >> 7;
    W1T[nn * 128 + k] = f2bf(W1[k * 256 + nn]);
  } else if (gid < 32768 + 8192) {
    int g2 = gid - 32768;
    int k = g2 & 255, c = g2 >> 8;
    W2T[c * 256 + k] = f2bf(W2[k * 32 + c]);
  }
}

// ---------------- Layer 1 MFMA GEMM + fused el/er ----------------
__global__ __launch_bounds__(256) void k_gemm1(const unsigned short* __restrict__ xb,
                                               const unsigned short* __restrict__ W1T,
                                               const float* __restrict__ al,
                                               const float* __restrict__ ar,
                                               unsigned short* __restrict__ f1b,
                                               float* __restrict__ el,
                                               float* __restrict__ er, int n) {
  __shared__ __align__(16) unsigned short xs[64][136];
  __shared__ __align__(16) unsigned short ws[64][136];
  const int tid = threadIdx.x;
  const int m0 = blockIdx.x * 64;
  const int c0 = blockIdx.y * 64;

#pragma unroll
  for (int r = 0; r < 4; ++r) {
    int idx = r * 256 + tid;
    int m = idx >> 4, kc = idx & 15;
    int gn = m0 + m;
    ushort4 a0 = make_ushort4(0, 0, 0, 0), a1 = a0;
    if (gn < n) {
      const ushort4* p = (const ushort4*)(xb + (size_t)gn * 128 + kc * 8);
      a0 = p[0]; a1 = p[1];
    }
    *(ushort4*)(&xs[m][kc * 8]) = a0;
    *(ushort4*)(&xs[m][kc * 8 + 4]) = a1;
    const ushort4* q = (const ushort4*)(W1T + (size_t)(c0 + m) * 128 + kc * 8);
    *(ushort4*)(&ws[m][kc * 8]) = q[0];
    *(ushort4*)(&ws[m][kc * 8 + 4]) = q[1];
  }
  __syncthreads();

  const int wave = tid >> 6, lane = tid & 63;
  const int quad = lane >> 4, col16 = lane & 15;

  v4f acc[4];
#pragma unroll
  for (int nt = 0; nt < 4; ++nt) acc[nt] = (v4f){0.f, 0.f, 0.f, 0.f};

#pragma unroll
  for (int kc = 0; kc < 4; ++kc) {
    v8s a = *(const v8s*)(&xs[wave * 16 + col16][kc * 32 + quad * 8]);
#pragma unroll
    for (int nt = 0; nt < 4; ++nt) {
      v8s b = *(const v8s*)(&ws[nt * 16 + col16][kc * 32 + quad * 8]);
      acc[nt] = __builtin_amdgcn_mfma_f32_16x16x32_bf16(a, b, acc[nt], 0, 0, 0);
    }
  }

  float pel[4][2], per_r[4][2];
#pragma unroll
  for (int rg = 0; rg < 4; ++rg) {
    pel[rg][0] = pel[rg][1] = 0.f;
    per_r[rg][0] = per_r[rg][1] = 0.f;
  }
#pragma unroll
  for (int nt = 0; nt < 4; ++nt) {
    int gcol = c0 + nt * 16 + col16;
    float alv = al[gcol], arv = ar[gcol];
    int hh = nt >> 1;
#pragma unroll
    for (int rg = 0; rg < 4; ++rg) {
      int gn = m0 + wave * 16 + quad * 4 + rg;
      float v = acc[nt][rg];
      if (gn < n) f1b[(size_t)gn * 256 + gcol] = f2bf(v);
      pel[rg][hh] += v * alv;
      per_r[rg][hh] += v * arv;
    }
  }
#pragma unroll
  for (int off = 1; off < 16; off <<= 1) {
#pragma unroll
    for (int rg = 0; rg < 4; ++rg) {
#pragma unroll
      for (int hh = 0; hh < 2; ++hh) {
        pel[rg][hh] += __shfl_xor(pel[rg][hh], off, 64);
        per_r[rg][hh] += __shfl_xor(per_r[rg][hh], off, 64);
      }
    }
  }
  if (col16 == 0) {
    int hb = c0 >> 5;
#pragma unroll
    for (int rg = 0; rg < 4; ++rg) {
      int gn = m0 + wave * 16 + quad * 4 + rg;
      if (gn < n) {
#pragma unroll
        for (int hh = 0; hh < 2; ++hh) {
          el[gn * 8 + hb + hh] = pel[rg][hh];
          er[gn * 8 + hb + hh] = per_r[rg][hh];
        }
      }
    }
  }
}

// ---------------- Layer 1 aggregation: 2 edges per wave in flight ----------------
__global__ __launch_bounds__(256) void k_agg1(const unsigned short* __restrict__ f1b,
                                              const float* __restrict__ el,
                                              const float* __restrict__ er,
                                              const int* __restrict__ offsets,
                                              const int* __restrict__ counts,
                                              const int* __restrict__ csr_src,
                                              const float* __restrict__ b1,
                                              unsigned short* __restrict__ houtb, int n) {
  const int node = blockIdx.x;
  const int tid = threadIdx.x;
  const int hw = tid >> 5, lane32 = tid & 31;
  const int hd = lane32 >> 2;
  __shared__ __align__(16) float s_acc[8][260];
  __shared__ float s_dw[8][32];

  const int start = offsets[node], deg = counts[node];
  const float er0 = er[node * 8 + hd];
  float a[8];
#pragma unroll
  for (int d = 0; d < 8; ++d) a[d] = 0.f;
  float dw = 0.f;

  const unsigned short* fbase = f1b + lane32 * 8;

  int j0 = hw;
  int s0 = (j0 < deg) ? csr_src[start + j0] : -1;
  int s1 = (j0 + 8 < deg) ? csr_src[start + j0 + 8] : -1;
  while (j0 < deg) {
    int jn = j0 + 16;
    int sn0 = (jn < deg) ? csr_src[start + jn] : -1;
    int sn1 = (jn + 8 < deg) ? csr_src[start + jn + 8] : -1;
    uint4 vb0 = *(const uint4*)(fbase + (size_t)s0 * 256);
    float e0 = el[(size_t)s0 * 8 + hd];
    uint4 vb1 = make_uint4(0, 0, 0, 0);
    float e1 = 0.f;
    bool has1 = (s1 >= 0);
    if (has1) {
      vb1 = *(const uint4*)(fbase + (size_t)s1 * 256);
      e1 = el[(size_t)s1 * 8 + hd];
    }
    {
      float ev = e0 + er0;
      ev = (ev >= 0.f) ? ev : NEG_SLOPE * ev;
      float w = __expf(ev);
      a[0] += w * __uint_as_float(vb0.x << 16);
      a[1] += w * __uint_as_float(vb0.x & 0xffff0000u);
      a[2] += w * __uint_as_float(vb0.y << 16);
      a[3] += w * __uint_as_float(vb0.y & 0xffff0000u);
      a[4] += w * __uint_as_float(vb0.z << 16);
      a[5] += w * __uint_as_float(vb0.z & 0xffff0000u);
      a[6] += w * __uint_as_float(vb0.w << 16);
      a[7] += w * __uint_as_float(vb0.w & 0xffff0000u);
      dw += w;
    }
    if (has1) {
      float ev = e1 + er0;
      ev = (ev >= 0.f) ? ev : NEG_SLOPE * ev;
      float w = __expf(ev);
      a[0] += w * __uint_as_float(vb1.x << 16);
      a[1] += w * __uint_as_float(vb1.x & 0xffff0000u);
      a[2] += w * __uint_as_float(vb1.y << 16);
      a[3] += w * __uint_as_float(vb1.y & 0xffff0000u);
      a[4] += w * __uint_as_float(vb1.z << 16);
      a[5] += w * __uint_as_float(vb1.z & 0xffff0000u);
      a[6] += w * __uint_as_float(vb1.w << 16);
      a[7] += w * __uint_as_float(vb1.w & 0xffff0000u);
      dw += w;
    }
    s0 = sn0; s1 = sn1; j0 = jn;
  }

  *(float4*)(&s_acc[hw][lane32 * 8])     = make_float4(a[0], a[1], a[2], a[3]);
  *(float4*)(&s_acc[hw][lane32 * 8 + 4]) = make_float4(a[4], a[5], a[6], a[7]);
  s_dw[hw][lane32] = dw;
  __syncthreads();

  {
    int t = tid;
    float sum = 0.f;
#pragma unroll
    for (int g = 0; g < 8; ++g) sum += s_acc[g][t];
    int hh = t >> 5;
    float denom = 0.f;
#pragma unroll
    for (int g = 0; g < 8; ++g) denom += s_dw[g][hh * 4];
    float inv = (deg > 0) ? 1.f / denom : 0.f;
    float o = sum * inv + b1[t];
    o = (o > 0.f) ? o : (__expf(o) - 1.f);
    houtb[(size_t)node * 256 + t] = f2bf(o);
  }
}

// ---------------- Layer 2 MFMA GEMM + fused el2/er2 ----------------
__global__ __launch_bounds__(256) void k_gemm2(const unsigned short* __restrict__ hb,
                                               const unsigned short* __restrict__ W2T,
                                               const float* __restrict__ al2,
                                               const float* __restrict__ ar2,
                                               float* __restrict__ f2,
                                               float* __restrict__ el2,
                                               float* __restrict__ er2, int n) {
  __shared__ __align__(16) unsigned short xs[64][264];
  __shared__ __align__(16) unsigned short ws[32][264];
  const int tid = threadIdx.x;
  const int m0 = blockIdx.x * 64;

#pragma unroll
  for (int r = 0; r < 8; ++r) {
    int idx = r * 256 + tid;
    int m = idx >> 5, kc = idx & 31;
    int gn = m0 + m;
    ushort4 a0 = make_ushort4(0, 0, 0, 0), a1 = a0;
    if (gn < n) {
      const ushort4* p = (const ushort4*)(hb + (size_t)gn * 256 + kc * 8);
      a0 = p[0]; a1 = p[1];
    }
    *(ushort4*)(&xs[m][kc * 8]) = a0;
    *(ushort4*)(&xs[m][kc * 8 + 4]) = a1;
  }
#pragma unroll
  for (int r = 0; r < 4; ++r) {
    int idx = r * 256 + tid;
    int m = idx >> 5, kc = idx & 31;
    const ushort4* q = (const ushort4*)(W2T + (size_t)m * 256 + kc * 8);
    *(ushort4*)(&ws[m][kc * 8]) = q[0];
    *(ushort4*)(&ws[m][kc * 8 + 4]) = q[1];
  }
  __syncthreads();

  const int wave = tid >> 6, lane = tid & 63;
  const int quad = lane >> 4, col16 = lane & 15;

  v4f acc[2];
  acc[0] = (v4f){0.f, 0.f, 0.f, 0.f};
  acc[1] = (v4f){0.f, 0.f, 0.f, 0.f};

#pragma unroll
  for (int kc = 0; kc < 8; ++kc) {
    v8s a = *(const v8s*)(&xs[wave * 16 + col16][kc * 32 + quad * 8]);
#pragma unroll
    for (int nt = 0; nt < 2; ++nt) {
      v8s b = *(const v8s*)(&ws[nt * 16 + col16][kc * 32 + quad * 8]);
      acc[nt] = __builtin_amdgcn_mfma_f32_16x16x32_bf16(a, b, acc[nt], 0, 0, 0);
    }
  }

  float pel[4], per_r[4];
#pragma unroll
  for (int rg = 0; rg < 4; ++rg) { pel[rg] = 0.f; per_r[rg] = 0.f; }
#pragma unroll
  for (int nt = 0; nt < 2; ++nt) {
    int gcol = nt * 16 + col16;
    float alv = al2[gcol], arv = ar2[gcol];
#pragma unroll
    for (int rg = 0; rg < 4; ++rg) {
      int gn = m0 + wave * 16 + quad * 4 + rg;
      float v = acc[nt][rg];
      if (gn < n) f2[(size_t)gn * 32 + gcol] = v;
      pel[rg] += v * alv;
      per_r[rg] += v * arv;
    }
  }
#pragma unroll
  for (int off = 1; off < 16; off <<= 1) {
#pragma unroll
    for (int rg = 0; rg < 4; ++rg) {
      pel[rg] += __shfl_xor(pel[rg], off, 64);
      per_r[rg] += __shfl_xor(per_r[rg], off, 64);
    }
  }
  if (col16 == 0) {
#pragma unroll
    for (int rg = 0; rg < 4; ++rg) {
      int gn = m0 + wave * 16 + quad * 4 + rg;
      if (gn < n) { el2[gn] = pel[rg]; er2[gn] = per_r[rg]; }
    }
  }
}

// ---------------- Layer 2 aggregation -> output [N,32] ----------------
__global__ __launch_bounds__(256) void k_agg2(const float4* __restrict__ f2_4,
                                              const float* __restrict__ el2,
                                              const float* __restrict__ er2,
                                              const int* __restrict__ offsets,
                                              const int* __restrict__ counts,
                                              const int* __restrict__ csr_src,
                                              const float4* __restrict__ b2_4,
                                              float4* __restrict__ out4, int n) {
  int wid = threadIdx.x >> 6, lane = threadIdx.x & 63;
  int node = blockIdx.x * 4 + wid;
  if (node >= n) return;
  int eg = lane >> 3, d4 = lane & 7;
  int start = offsets[node], deg = counts[node];
  float er0 = er2[node];
  float4 acc = make_float4(0.f, 0.f, 0.f, 0.f);
  float dw = 0.f;
  int j = eg;
  int sN = (j < deg) ? csr_src[start + j] : 0;
  while (j < deg) {
    int s = sN;
    int j2 = j + 8;
    sN = (j2 < deg) ? csr_src[start + j2] : 0;
    float ev = el2[s] + er0;
    ev = (ev >= 0.f) ? ev : NEG_SLOPE * ev;
    float w = __expf(ev);
    float4 v = f2_4[(size_t)s * 8 + d4];
    acc.x += w * v.x; acc.y += w * v.y; acc.z += w * v.z; acc.w += w * v.w;
    dw += w;
    j = j2;
  }
#pragma unroll
  for (int off = 8; off <= 32; off <<= 1) {
    acc.x += __shfl_xor(acc.x, off, 64);
    acc.y += __shfl_xor(acc.y, off, 64);
    acc.z += __shfl_xor(acc.z, off, 64);
    acc.w += __shfl_xor(acc.w, off, 64);
    dw += __shfl_xor(dw, off, 64);
  }
  if (eg == 0) {
    float inv = (deg > 0) ? 1.f / dw : 0.f;
    float4 b = b2_4[d4];
    float4 r;
    r.x = acc.x * inv + b.x;
    r.y = acc.y * inv + b.y;
    r.z = acc.z * inv + b.z;
    r.w = acc.w * inv + b.w;
    out4[(size_t)node * 8 + d4] = r;
  }
}

// ---------------- launch ----------------

extern "C" void kernel_launch(void* const* d_in, const int* in_sizes, int n_in,
                              void* d_out, int out_size, void* d_ws, size_t ws_size,
                              hipStream_t stream) {
  const float* x   = (const float*)d_in[0];
  const int*   src = (const int*)d_in[1];
  const int*   dst = (const int*)d_in[2];
  const float* W1  = (const float*)d_in[3];
  const float* al1 = (const float*)d_in[4];
  const float* ar1 = (const float*)d_in[5];
  const float* b1  = (const float*)d_in[6];
  const float* W2  = (const float*)d_in[7];
  const float* al2 = (const float*)d_in[8];
  const float* ar2 = (const float*)d_in[9];
  const float* b2  = (const float*)d_in[10];
  float* out = (float*)d_out;

  int N = in_sizes[0] / 128;
  int E = in_sizes[1];

  char* w = (char*)d_ws;
  auto alloc = [&](size_t nbytes) -> void* {
    void* p = (void*)w;
    w += ((nbytes + 255) / 256) * 256;
    return p;
  };
  unsigned short* xb  = (unsigned short*)alloc((size_t)N * 128 * 2);
  unsigned short* W1T = (unsigned short*)alloc(256 * 128 * 2);
  unsigned short* W2T = (unsigned short*)alloc(32 * 256 * 2);
  unsigned short* f1b = (unsigned short*)alloc((size_t)N * 256 * 2);
  unsigned short* hb  = (unsigned short*)alloc((size_t)N * 256 * 2);
  float* el1  = (float*)alloc((size_t)N * 8 * 4);
  float* er1  = (float*)alloc((size_t)N * 8 * 4);
  float* f2   = (float*)alloc((size_t)N * 32 * 4);
  float* el2  = (float*)alloc((size_t)N * 4);
  float* er2  = (float*)alloc((size_t)N * 4);
  int* counts  = (int*)alloc((size_t)N * 4);
  int* offsets = (int*)alloc((size_t)N * 4);
  int* cursor  = (int*)alloc((size_t)N * 4);
  int* total   = (int*)alloc(4);
  int* csr_src = (int*)alloc((size_t)E * 4);

  hipLaunchKernelGGL(k_zero2, dim3((N + 255) / 256), dim3(256), 0, stream, counts, N, total);
  hipLaunchKernelGGL(k_count, dim3((E + 255) / 256), dim3(256), 0, stream, dst, counts, E);
  hipLaunchKernelGGL(k_offsets, dim3((N + 255) / 256), dim3(256), 0, stream, counts, offsets, cursor, total, N);
  hipLaunchKernelGGL(k_fill, dim3((E + 255) / 256), dim3(256), 0, stream, src, dst, cursor, csr_src, E);
  hipLaunchKernelGGL(k_castx, dim3((N * 128 / 4 + 255) / 256), dim3(256), 0, stream,
                     (const float4*)x, (ushort4*)xb, N * 128 / 4);
  hipLaunchKernelGGL(k_prepW, dim3((32768 + 8192 + 255) / 256), dim3(256), 0, stream, W1, W2, W1T, W2T);
  hipLaunchKernelGGL(k_gemm1, dim3((N + 63) / 64, 4), dim3(256), 0, stream, xb, W1T, al1, ar1, f1b, el1, er1, N);
  hipLaunchKernelGGL(k_agg1, dim3(N), dim3(256), 0, stream, f1b, el1, er1, offsets, counts, csr_src, b1, hb, N);
  hipLaunchKernelGGL(k_gemm2, dim3((N + 63) / 64), dim3(256), 0, stream, hb, W2T, al2, ar2, f2, el2, er2, N);
  hipLaunchKernelGGL(k_agg2, dim3((N + 3) / 4), dim3(256), 0, stream, (const float4*)f2, el2, er2, offsets,
                     counts, csr_src, (const float4*)b2, (float4*)out, N);
}

// Round 7
// 309.959 us; speedup vs baseline: 2.4269x; 1.0115x over previous
//
#include <hip/hip_runtime.h>
#include <math.h>

#define NEG_SLOPE 0.2f

typedef short v8s __attribute__((ext_vector_type(8)));   // 8 bf16 in 4 VGPRs
typedef float v4f __attribute__((ext_vector_type(4)));
typedef float v2f __attribute__((ext_vector_type(2)));

__device__ inline unsigned short f2bf(float x) {
  unsigned u = __float_as_uint(x);
  u += 0x7fffu + ((u >> 16) & 1u);  // RNE
  return (unsigned short)(u >> 16);
}

// ---------------- CSR build ----------------

__global__ void k_zero2(int* __restrict__ counts, int n, int* __restrict__ total) {
  int i = blockIdx.x * 256 + threadIdx.x;
  if (i < n) counts[i] = 0;
  if (i == 0) *total = 0;
}

__global__ void k_count(const int* __restrict__ dst, int* __restrict__ counts, int E) {
  int i = blockIdx.x * 256 + threadIdx.x;
  if (i < E) atomicAdd(&counts[dst[i]], 1);
}

__global__ void k_offsets(const int* __restrict__ counts, int* __restrict__ offsets,
                          int* __restrict__ cursor, int* __restrict__ total, int n) {
  int i = blockIdx.x * 256 + threadIdx.x;
  if (i < n) {
    int c = counts[i];
    int o = atomicAdd(total, c);
    offsets[i] = o;
    cursor[i] = o;
  }
}

__global__ void k_fill(const int* __restrict__ src, const int* __restrict__ dst,
                       int* __restrict__ cursor, int* __restrict__ csr_src, int E) {
  int i = blockIdx.x * 256 + threadIdx.x;
  if (i < E) {
    int d = dst[i];
    int pos = atomicAdd(&cursor[d], 1);
    csr_src[pos] = src[i];
  }
}

// ---------------- prep: W1/W2 -> transposed bf16 ----------------

__global__ void k_prepW(const float* __restrict__ W1, const float* __restrict__ W2,
                        unsigned short* __restrict__ W1T, unsigned short* __restrict__ W2T) {
  int gid = blockIdx.x * 256 + threadIdx.x;
  if (gid < 32768) {
    int k = gid & 127, nn = gid >> 7;
    W1T[nn * 128 + k] = f2bf(W1[k * 256 + nn]);
  } else if (gid < 32768 + 8192) {
    int g2 = gid - 32768;
    int k = g2 & 255, c = g2 >> 8;
    W2T[c * 256 + k] = f2bf(W2[k * 32 + c]);
  }
}

// ---------------- Layer 1 MFMA GEMM (fp32 x staged->bf16, all 256 cols per block) + fused el/er ----------------
__global__ __launch_bounds__(256) void k_gemm1(const float* __restrict__ x,
                                               const unsigned short* __restrict__ W1T,
                                               const float* __restrict__ al,
                                               const float* __restrict__ ar,
                                               unsigned short* __restrict__ f1b,
                                               float* __restrict__ el,
                                               float* __restrict__ er, int n) {
  __shared__ __align__(16) unsigned short xs[64][136];
  __shared__ __align__(16) unsigned short ws[64][136];
  const int tid = threadIdx.x;
  const int m0 = blockIdx.x * 64;

  // stage x (fp32 -> bf16): 64 rows x 32 float4 chunks = 2048, 8 rounds
#pragma unroll
  for (int r = 0; r < 8; ++r) {
    int idx = r * 256 + tid;
    int m = idx >> 5, c4 = idx & 31;
    int gn = m0 + m;
    float4 v = make_float4(0.f, 0.f, 0.f, 0.f);
    if (gn < n) v = *(const float4*)(x + (size_t)gn * 128 + c4 * 4);
    ushort4 pk;
    pk.x = f2bf(v.x); pk.y = f2bf(v.y); pk.z = f2bf(v.z); pk.w = f2bf(v.w);
    *(ushort4*)(&xs[m][c4 * 4]) = pk;
  }

  const int wave = tid >> 6, lane = tid & 63;
  const int quad = lane >> 4, col16 = lane & 15;

  for (int cb = 0; cb < 4; ++cb) {
    const int c0 = cb * 64;
    // stage W tile: 64 cols x 16 chunks of 8 bf16 = 1024, 4 rounds
#pragma unroll
    for (int r = 0; r < 4; ++r) {
      int idx = r * 256 + tid;
      int m = idx >> 4, kc = idx & 15;
      const ushort4* q = (const ushort4*)(W1T + (size_t)(c0 + m) * 128 + kc * 8);
      *(ushort4*)(&ws[m][kc * 8]) = q[0];
      *(ushort4*)(&ws[m][kc * 8 + 4]) = q[1];
    }
    __syncthreads();

    v4f acc[4];
#pragma unroll
    for (int nt = 0; nt < 4; ++nt) acc[nt] = (v4f){0.f, 0.f, 0.f, 0.f};

#pragma unroll
    for (int kc = 0; kc < 4; ++kc) {
      v8s a = *(const v8s*)(&xs[wave * 16 + col16][kc * 32 + quad * 8]);
#pragma unroll
      for (int nt = 0; nt < 4; ++nt) {
        v8s b = *(const v8s*)(&ws[nt * 16 + col16][kc * 32 + quad * 8]);
        acc[nt] = __builtin_amdgcn_mfma_f32_16x16x32_bf16(a, b, acc[nt], 0, 0, 0);
      }
    }

    float pel[4][2], per_r[4][2];
#pragma unroll
    for (int rg = 0; rg < 4; ++rg) {
      pel[rg][0] = pel[rg][1] = 0.f;
      per_r[rg][0] = per_r[rg][1] = 0.f;
    }
#pragma unroll
    for (int nt = 0; nt < 4; ++nt) {
      int gcol = c0 + nt * 16 + col16;
      float alv = al[gcol], arv = ar[gcol];
      int hh = nt >> 1;
#pragma unroll
      for (int rg = 0; rg < 4; ++rg) {
        int gn = m0 + wave * 16 + quad * 4 + rg;
        float v = acc[nt][rg];
        if (gn < n) f1b[(size_t)gn * 256 + gcol] = f2bf(v);
        pel[rg][hh] += v * alv;
        per_r[rg][hh] += v * arv;
      }
    }
#pragma unroll
    for (int off = 1; off < 16; off <<= 1) {
#pragma unroll
      for (int rg = 0; rg < 4; ++rg) {
#pragma unroll
        for (int hh = 0; hh < 2; ++hh) {
          pel[rg][hh] += __shfl_xor(pel[rg][hh], off, 64);
          per_r[rg][hh] += __shfl_xor(per_r[rg][hh], off, 64);
        }
      }
    }
    if (col16 == 0) {
      int hb = cb * 2;
#pragma unroll
      for (int rg = 0; rg < 4; ++rg) {
        int gn = m0 + wave * 16 + quad * 4 + rg;
        if (gn < n) {
#pragma unroll
          for (int hh = 0; hh < 2; ++hh) {
            el[gn * 8 + hb + hh] = pel[rg][hh];
            er[gn * 8 + hb + hh] = per_r[rg][hh];
          }
        }
      }
    }
    __syncthreads();  // protect ws before restage
  }
}

// ---------------- Layer 1 aggregation: 2 edges per wave in flight, packed fp32 FMA ----------------
__global__ __launch_bounds__(256) void k_agg1(const unsigned short* __restrict__ f1b,
                                              const float* __restrict__ el,
                                              const float* __restrict__ er,
                                              const int* __restrict__ offsets,
                                              const int* __restrict__ counts,
                                              const int* __restrict__ csr_src,
                                              const float* __restrict__ b1,
                                              unsigned short* __restrict__ houtb, int n) {
  const int node = blockIdx.x;
  const int tid = threadIdx.x;
  const int hw = tid >> 5, lane32 = tid & 31;
  const int hd = lane32 >> 2;
  __shared__ __align__(16) float s_acc[8][260];
  __shared__ float s_dw[8][32];

  const int start = offsets[node], deg = counts[node];
  const float er0 = er[node * 8 + hd];
  v2f A0 = (v2f){0.f, 0.f}, A1 = A0, A2 = A0, A3 = A0;
  float dw = 0.f;

  const unsigned short* fbase = f1b + lane32 * 8;

  int j0 = hw;
  int s0 = (j0 < deg) ? csr_src[start + j0] : -1;
  int s1 = (j0 + 8 < deg) ? csr_src[start + j0 + 8] : -1;
  while (j0 < deg) {
    int jn = j0 + 16;
    int sn0 = (jn < deg) ? csr_src[start + jn] : -1;
    int sn1 = (jn + 8 < deg) ? csr_src[start + jn + 8] : -1;
    uint4 vb0 = *(const uint4*)(fbase + (size_t)s0 * 256);
    float e0 = el[(size_t)s0 * 8 + hd];
    uint4 vb1 = make_uint4(0, 0, 0, 0);
    float e1 = 0.f;
    bool has1 = (s1 >= 0);
    if (has1) {
      vb1 = *(const uint4*)(fbase + (size_t)s1 * 256);
      e1 = el[(size_t)s1 * 8 + hd];
    }
    {
      float ev = e0 + er0;
      ev = (ev >= 0.f) ? ev : NEG_SLOPE * ev;
      float w = __expf(ev);
      v2f u0 = (v2f){__uint_as_float(vb0.x << 16), __uint_as_float(vb0.x & 0xffff0000u)};
      v2f u1 = (v2f){__uint_as_float(vb0.y << 16), __uint_as_float(vb0.y & 0xffff0000u)};
      v2f u2 = (v2f){__uint_as_float(vb0.z << 16), __uint_as_float(vb0.z & 0xffff0000u)};
      v2f u3 = (v2f){__uint_as_float(vb0.w << 16), __uint_as_float(vb0.w & 0xffff0000u)};
      A0 += u0 * w; A1 += u1 * w; A2 += u2 * w; A3 += u3 * w;
      dw += w;
    }
    if (has1) {
      float ev = e1 + er0;
      ev = (ev >= 0.f) ? ev : NEG_SLOPE * ev;
      float w = __expf(ev);
      v2f u0 = (v2f){__uint_as_float(vb1.x << 16), __uint_as_float(vb1.x & 0xffff0000u)};
      v2f u1 = (v2f){__uint_as_float(vb1.y << 16), __uint_as_float(vb1.y & 0xffff0000u)};
      v2f u2 = (v2f){__uint_as_float(vb1.z << 16), __uint_as_float(vb1.z & 0xffff0000u)};
      v2f u3 = (v2f){__uint_as_float(vb1.w << 16), __uint_as_float(vb1.w & 0xffff0000u)};
      A0 += u0 * w; A1 += u1 * w; A2 += u2 * w; A3 += u3 * w;
      dw += w;
    }
    s0 = sn0; s1 = sn1; j0 = jn;
  }

  *(float4*)(&s_acc[hw][lane32 * 8])     = make_float4(A0.x, A0.y, A1.x, A1.y);
  *(float4*)(&s_acc[hw][lane32 * 8 + 4]) = make_float4(A2.x, A2.y, A3.x, A3.y);
  s_dw[hw][lane32] = dw;
  __syncthreads();

  {
    int t = tid;
    float sum = 0.f;
#pragma unroll
    for (int g = 0; g < 8; ++g) sum += s_acc[g][t];
    int hh = t >> 5;
    float denom = 0.f;
#pragma unroll
    for (int g = 0; g < 8; ++g) denom += s_dw[g][hh * 4];
    float inv = (deg > 0) ? 1.f / denom : 0.f;
    float o = sum * inv + b1[t];
    o = (o > 0.f) ? o : (__expf(o) - 1.f);
    houtb[(size_t)node * 256 + t] = f2bf(o);
  }
}

// ---------------- Layer 2 MFMA GEMM (bf16 f2 out) + fused el2/er2 ----------------
__global__ __launch_bounds__(256) void k_gemm2(const unsigned short* __restrict__ hb,
                                               const unsigned short* __restrict__ W2T,
                                               const float* __restrict__ al2,
                                               const float* __restrict__ ar2,
                                               unsigned short* __restrict__ f2b,
                                               float* __restrict__ el2,
                                               float* __restrict__ er2, int n) {
  __shared__ __align__(16) unsigned short xs[64][264];
  __shared__ __align__(16) unsigned short ws[32][264];
  const int tid = threadIdx.x;
  const int m0 = blockIdx.x * 64;

#pragma unroll
  for (int r = 0; r < 8; ++r) {
    int idx = r * 256 + tid;
    int m = idx >> 5, kc = idx & 31;
    int gn = m0 + m;
    ushort4 a0 = make_ushort4(0, 0, 0, 0), a1 = a0;
    if (gn < n) {
      const ushort4* p = (const ushort4*)(hb + (size_t)gn * 256 + kc * 8);
      a0 = p[0]; a1 = p[1];
    }
    *(ushort4*)(&xs[m][kc * 8]) = a0;
    *(ushort4*)(&xs[m][kc * 8 + 4]) = a1;
  }
#pragma unroll
  for (int r = 0; r < 4; ++r) {
    int idx = r * 256 + tid;
    int m = idx >> 5, kc = idx & 31;
    const ushort4* q = (const ushort4*)(W2T + (size_t)m * 256 + kc * 8);
    *(ushort4*)(&ws[m][kc * 8]) = q[0];
    *(ushort4*)(&ws[m][kc * 8 + 4]) = q[1];
  }
  __syncthreads();

  const int wave = tid >> 6, lane = tid & 63;
  const int quad = lane >> 4, col16 = lane & 15;

  v4f acc[2];
  acc[0] = (v4f){0.f, 0.f, 0.f, 0.f};
  acc[1] = (v4f){0.f, 0.f, 0.f, 0.f};

#pragma unroll
  for (int kc = 0; kc < 8; ++kc) {
    v8s a = *(const v8s*)(&xs[wave * 16 + col16][kc * 32 + quad * 8]);
#pragma unroll
    for (int nt = 0; nt < 2; ++nt) {
      v8s b = *(const v8s*)(&ws[nt * 16 + col16][kc * 32 + quad * 8]);
      acc[nt] = __builtin_amdgcn_mfma_f32_16x16x32_bf16(a, b, acc[nt], 0, 0, 0);
    }
  }

  float pel[4], per_r[4];
#pragma unroll
  for (int rg = 0; rg < 4; ++rg) { pel[rg] = 0.f; per_r[rg] = 0.f; }
#pragma unroll
  for (int nt = 0; nt < 2; ++nt) {
    int gcol = nt * 16 + col16;
    float alv = al2[gcol], arv = ar2[gcol];
#pragma unroll
    for (int rg = 0; rg < 4; ++rg) {
      int gn = m0 + wave * 16 + quad * 4 + rg;
      float v = acc[nt][rg];
      if (gn < n) f2b[(size_t)gn * 32 + gcol] = f2bf(v);
      pel[rg] += v * alv;
      per_r[rg] += v * arv;
    }
  }
#pragma unroll
  for (int off = 1; off < 16; off <<= 1) {
#pragma unroll
    for (int rg = 0; rg < 4; ++rg) {
      pel[rg] += __shfl_xor(pel[rg], off, 64);
      per_r[rg] += __shfl_xor(per_r[rg], off, 64);
    }
  }
  if (col16 == 0) {
#pragma unroll
    for (int rg = 0; rg < 4; ++rg) {
      int gn = m0 + wave * 16 + quad * 4 + rg;
      if (gn < n) { el2[gn] = pel[rg]; er2[gn] = per_r[rg]; }
    }
  }
}

// ---------------- Layer 2 aggregation: bf16 f2, 16-lane edge groups, unroll x2 ----------------
__global__ __launch_bounds__(256) void k_agg2(const unsigned short* __restrict__ f2b,
                                              const float* __restrict__ el2,
                                              const float* __restrict__ er2,
                                              const int* __restrict__ offsets,
                                              const int* __restrict__ counts,
                                              const int* __restrict__ csr_src,
                                              const float* __restrict__ b2,
                                              float* __restrict__ out, int n) {
  int wid = threadIdx.x >> 6, lane = threadIdx.x & 63;
  int node = blockIdx.x * 4 + wid;
  if (node >= n) return;
  int eg = lane >> 4, l16 = lane & 15;
  int start = offsets[node], deg = counts[node];
  float er0 = er2[node];
  float a0 = 0.f, a1 = 0.f, dw = 0.f;

  const unsigned short* fbase = f2b + l16 * 2;

  int j = eg;
  int s0 = (j < deg) ? csr_src[start + j] : -1;
  int s1 = (j + 4 < deg) ? csr_src[start + j + 4] : -1;
  while (j < deg) {
    int jn = j + 8;
    int sn0 = (jn < deg) ? csr_src[start + jn] : -1;
    int sn1 = (jn + 4 < deg) ? csr_src[start + jn + 4] : -1;
    unsigned vb0 = *(const unsigned*)(fbase + (size_t)s0 * 32);
    float e0 = el2[s0];
    unsigned vb1 = 0; float e1 = 0.f;
    bool has1 = (s1 >= 0);
    if (has1) {
      vb1 = *(const unsigned*)(fbase + (size_t)s1 * 32);
      e1 = el2[s1];
    }
    {
      float ev = e0 + er0;
      ev = (ev >= 0.f) ? ev : NEG_SLOPE * ev;
      float w = __expf(ev);
      a0 += w * __uint_as_float(vb0 << 16);
      a1 += w * __uint_as_float(vb0 & 0xffff0000u);
      dw += w;
    }
    if (has1) {
      float ev = e1 + er0;
      ev = (ev >= 0.f) ? ev : NEG_SLOPE * ev;
      float w = __expf(ev);
      a0 += w * __uint_as_float(vb1 << 16);
      a1 += w * __uint_as_float(vb1 & 0xffff0000u);
      dw += w;
    }
    s0 = sn0; s1 = sn1; j = jn;
  }
#pragma unroll
  for (int off = 16; off <= 32; off <<= 1) {
    a0 += __shfl_xor(a0, off, 64);
    a1 += __shfl_xor(a1, off, 64);
    dw += __shfl_xor(dw, off, 64);
  }
  if (eg == 0) {
    float inv = (deg > 0) ? 1.f / dw : 0.f;
    float2 r;
    r.x = a0 * inv + b2[l16 * 2];
    r.y = a1 * inv + b2[l16 * 2 + 1];
    *(float2*)(out + (size_t)node * 32 + l16 * 2) = r;
  }
}

// ---------------- launch ----------------

extern "C" void kernel_launch(void* const* d_in, const int* in_sizes, int n_in,
                              void* d_out, int out_size, void* d_ws, size_t ws_size,
                              hipStream_t stream) {
  const float* x   = (const float*)d_in[0];
  const int*   src = (const int*)d_in[1];
  const int*   dst = (const int*)d_in[2];
  const float* W1  = (const float*)d_in[3];
  const float* al1 = (const float*)d_in[4];
  const float* ar1 = (const float*)d_in[5];
  const float* b1  = (const float*)d_in[6];
  const float* W2  = (const float*)d_in[7];
  const float* al2 = (const float*)d_in[8];
  const float* ar2 = (const float*)d_in[9];
  const float* b2  = (const float*)d_in[10];
  float* out = (float*)d_out;

  int N = in_sizes[0] / 128;
  int E = in_sizes[1];

  char* w = (char*)d_ws;
  auto alloc = [&](size_t nbytes) -> void* {
    void* p = (void*)w;
    w += ((nbytes + 255) / 256) * 256;
    return p;
  };
  unsigned short* W1T = (unsigned short*)alloc(256 * 128 * 2);
  unsigned short* W2T = (unsigned short*)alloc(32 * 256 * 2);
  unsigned short* f1b = (unsigned short*)alloc((size_t)N * 256 * 2);
  unsigned short* hb  = (unsigned short*)alloc((size_t)N * 256 * 2);
  unsigned short* f2b = (unsigned short*)alloc((size_t)N * 32 * 2);
  float* el1  = (float*)alloc((size_t)N * 8 * 4);
  float* er1  = (float*)alloc((size_t)N * 8 * 4);
  float* el2  = (float*)alloc((size_t)N * 4);
  float* er2  = (float*)alloc((size_t)N * 4);
  int* counts  = (int*)alloc((size_t)N * 4);
  int* offsets = (int*)alloc((size_t)N * 4);
  int* cursor  = (int*)alloc((size_t)N * 4);
  int* total   = (int*)alloc(4);
  int* csr_src = (int*)alloc((size_t)E * 4);

  hipLaunchKernelGGL(k_zero2, dim3((N + 255) / 256), dim3(256), 0, stream, counts, N, total);
  hipLaunchKernelGGL(k_count, dim3((E + 255) / 256), dim3(256), 0, stream, dst, counts, E);
  hipLaunchKernelGGL(k_offsets, dim3((N + 255) / 256), dim3(256), 0, stream, counts, offsets, cursor, total, N);
  hipLaunchKernelGGL(k_fill, dim3((E + 255) / 256), dim3(256), 0, stream, src, dst, cursor, csr_src, E);
  hipLaunchKernelGGL(k_prepW, dim3((32768 + 8192 + 255) / 256), dim3(256), 0, stream, W1, W2, W1T, W2T);
  hipLaunchKernelGGL(k_gemm1, dim3((N + 63) / 64), dim3(256), 0, stream, x, W1T, al1, ar1, f1b, el1, er1, N);
  hipLaunchKernelGGL(k_agg1, dim3(N), dim3(256), 0, stream, f1b, el1, er1, offsets, counts, csr_src, b1, hb, N);
  hipLaunchKernelGGL(k_gemm2, dim3((N + 63) / 64), dim3(256), 0, stream, hb, W2T, al2, ar2, f2b, el2, er2, N);
  hipLaunchKernelGGL(k_agg2, dim3((N + 3) / 4), dim3(256), 0, stream, f2b, el2, er2, offsets, counts, csr_src,
                     b2, out, N);
}